// Round 15
// baseline (319.140 us; speedup 1.0000x reference)
//
#include <hip/hip_runtime.h>
#include <hip/hip_bf16.h>
#include <stdint.h>

#define DEV __device__ __forceinline__

typedef short     s16x8  __attribute__((ext_vector_type(8)));
typedef __bf16    bf16v8 __attribute__((ext_vector_type(8)));
typedef float     f32x4  __attribute__((ext_vector_type(4)));
typedef float     f32x16 __attribute__((ext_vector_type(16)));
typedef unsigned int u32x2 __attribute__((ext_vector_type(2)));

// ---------- helpers ----------
DEV unsigned short f2bf(float x) {
    uint32_t u = __float_as_uint(x);
    uint32_t r = (u + 0x7FFFu + ((u >> 16) & 1u)) >> 16;
    return (unsigned short)r;
}
DEV float bf2f(uint32_t u) { return __uint_as_float(u << 16); }

DEV void gload_lds16(const void* g, void* l) {
    __builtin_amdgcn_global_load_lds((const __attribute__((address_space(1))) void*)g,
                                     (__attribute__((address_space(3))) void*)l,
                                     16, 0, 0);
}

DEV f32x4 mfma16(s16x8 a, s16x8 b, f32x4 c) {
    return __builtin_amdgcn_mfma_f32_16x16x32_bf16(
        __builtin_bit_cast(bf16v8, a), __builtin_bit_cast(bf16v8, b), c, 0, 0, 0);
}
DEV f32x16 mfma32(s16x8 a, s16x8 b, f32x16 c) {
    return __builtin_amdgcn_mfma_f32_32x32x16_bf16(
        __builtin_bit_cast(bf16v8, a), __builtin_bit_cast(bf16v8, b), c, 0, 0, 0);
}

DEV uint32_t cvtpk_bf16(float lo, float hi) {
    uint32_t r;
    asm volatile("v_cvt_pk_bf16_f32 %0, %1, %2" : "=v"(r) : "v"(lo), "v"(hi));
    return r;
}

DEV u32x2 pl32swap(uint32_t a, uint32_t b) {
    return __builtin_amdgcn_permlane32_swap(a, b, false, false);
}
DEV float cross_max(float x) {
    u32x2 r = pl32swap(__float_as_uint(x), __float_as_uint(x));
    return fmaxf(__uint_as_float(r[0]), __uint_as_float(r[1]));
}
DEV float cross_sum(float x) {
    u32x2 r = pl32swap(__float_as_uint(x), __float_as_uint(x));
    return __uint_as_float(r[0]) + __uint_as_float(r[1]);
}

DEV void barx() {
    asm volatile("" ::: "memory");
    __builtin_amdgcn_s_barrier();
    __builtin_amdgcn_sched_barrier(0);
    asm volatile("" ::: "memory");
}

// ---------- elementwise f32 -> bf16 ----------
__global__ void f32_to_bf16_k(const float* __restrict__ in, short* __restrict__ out, int n8) {
    int i = blockIdx.x * blockDim.x + threadIdx.x;
    if (i >= n8) return;
    const float4 a = *(const float4*)(in + (size_t)i * 8);
    const float4 b = *(const float4*)(in + (size_t)i * 8 + 4);
    uint4 w;
    w.x = (uint32_t)f2bf(a.x) | ((uint32_t)f2bf(a.y) << 16);
    w.y = (uint32_t)f2bf(a.z) | ((uint32_t)f2bf(a.w) << 16);
    w.z = (uint32_t)f2bf(b.x) | ((uint32_t)f2bf(b.y) << 16);
    w.w = (uint32_t)f2bf(b.z) | ((uint32_t)f2bf(b.w) << 16);
    *(uint4*)(out + (size_t)i * 8) = w;
}

// ---------- tiled transpose f32 (R x C) -> bf16 (C x R) ----------
__global__ __launch_bounds__(256) void transpose_f32_bf16_k(
    const float* __restrict__ in, size_t in_batch, int ld_in,
    short* __restrict__ out, size_t out_batch, int ld_out) {
    __shared__ float tile[64][65];
    const float* ip = in + (size_t)blockIdx.z * in_batch;
    short* op = out + (size_t)blockIdx.z * out_batch;
    const int c0 = blockIdx.x * 64, r0 = blockIdx.y * 64;
    const int t = threadIdx.x;
    const int cc4 = (t & 15) * 4;
    const int rr  = t >> 4;
#pragma unroll
    for (int p = 0; p < 4; ++p) {
        int r = rr + p * 16;
        float4 v = *(const float4*)(ip + (size_t)(r0 + r) * ld_in + c0 + cc4);
        tile[r][cc4 + 0] = v.x; tile[r][cc4 + 1] = v.y;
        tile[r][cc4 + 2] = v.z; tile[r][cc4 + 3] = v.w;
    }
    __syncthreads();
#pragma unroll
    for (int p = 0; p < 4; ++p) {
        int oc  = (t >> 4) + p * 16;
        int rr4 = (t & 15) * 4;
        ushort4 w;
        w.x = f2bf(tile[rr4 + 0][oc]);
        w.y = f2bf(tile[rr4 + 1][oc]);
        w.z = f2bf(tile[rr4 + 2][oc]);
        w.w = f2bf(tile[rr4 + 3][oc]);
        *(ushort4*)(op + (size_t)(c0 + oc) * ld_out + r0 + rr4) = w;
    }
}

// ---------- tiled transpose bf16 (R x C) -> bf16 (C x R) ----------
__global__ __launch_bounds__(256) void transpose_bf16_k(
    const short* __restrict__ in, size_t in_batch, int ld_in,
    short* __restrict__ out, size_t out_batch, int ld_out) {
    __shared__ short tile[64][72];
    const short* ip = in + (size_t)blockIdx.z * in_batch;
    short* op = out + (size_t)blockIdx.z * out_batch;
    const int c0 = blockIdx.x * 64, r0 = blockIdx.y * 64;
    const int t = threadIdx.x;
    const int cc = (t & 7) * 8;
    const int rr = t >> 3;
#pragma unroll
    for (int p = 0; p < 2; ++p) {
        int r = rr + p * 32;
        s16x8 v = *(const s16x8*)(ip + (size_t)(r0 + r) * ld_in + c0 + cc);
        *(s16x8*)&tile[r][cc] = v;
    }
    __syncthreads();
    const int oc = t >> 2;
    const int rb = (t & 3) * 16;
    s16x8 w0, w1;
#pragma unroll
    for (int j = 0; j < 8; ++j) w0[j] = tile[rb + j][oc];
#pragma unroll
    for (int j = 0; j < 8; ++j) w1[j] = tile[rb + 8 + j][oc];
    *(s16x8*)(op + (size_t)(c0 + oc) * ld_out + r0 + rb) = w0;
    *(s16x8*)(op + (size_t)(c0 + oc) * ld_out + r0 + rb + 8) = w1;
}

// ---------- bias concat ----------
__global__ void concat_bias_k(const float* __restrict__ bq, const float* __restrict__ bk,
                              const float* __restrict__ bv, float* __restrict__ o) {
    int i = blockIdx.x * 256 + threadIdx.x;
    if (i < 2048)       o[i] = bq[i];
    else if (i < 2560)  o[i] = bk[i - 2048];
    else if (i < 3072)  o[i] = bv[i - 2560];
}

// ---------- GEMM v5 (r12-proven): 2-phase counted-vmcnt ----------
template<int TAG, bool OUTBF, int NF>
__global__ __launch_bounds__(512, 2) void gemm256_k(
    const short* __restrict__ A, const short* __restrict__ Bt,
    const float* __restrict__ bias, void* __restrict__ Cv,
    int M, int N, int K) {
    __shared__ short As[2][16384];
    __shared__ short Bs[2][NF * 4096];
    const int tid = threadIdx.x;
    const int gx = gridDim.x;
    const int nwg = gx * gridDim.y;
    const int flat = blockIdx.y * gx + blockIdx.x;
    const int cpx = nwg >> 3;
    const int swz = (flat & 7) * cpx + (flat >> 3);
    const int m0 = (swz / gx) * 256, n0 = (swz % gx) * (NF * 64);
    const int lane = tid & 63, wid = tid >> 6;
    const int wm = wid >> 2, wn = wid & 3;
    const int lr = lane & 15, lg = lane >> 4;

    const int srow = tid >> 3;
    const int schunk = ((tid & 7) ^ (srow & 7)) << 3;
    const short* Ag = A  + (size_t)(m0 + srow) * K + schunk;
    const short* Bg = Bt + (size_t)(n0 + srow) * K + schunk;
    const int lwb = (tid & ~63) * 8;

    f32x4 acc[8][NF];
#pragma unroll
    for (int fr = 0; fr < 8; ++fr)
#pragma unroll
        for (int fc = 0; fc < NF; ++fc)
#pragma unroll
            for (int r = 0; r < 4; ++r) acc[fr][fc][r] = 0.f;

    const int nk = K >> 6;

#define SA(u, kt, dd) gload_lds16(Ag + (size_t)(u) * 64 * K + (kt) * 64, &As[dd][(u) * 4096 + lwb])
#define SB(u, kt, dd) gload_lds16(Bg + (size_t)(u) * 64 * K + (kt) * 64, &Bs[dd][(u) * 4096 + lwb])

    SA(0, 0, 0); SA(1, 0, 0); SA(2, 0, 0); SA(3, 0, 0);
#pragma unroll
    for (int u = 0; u < NF; ++u) SB(u, 0, 0);
    asm volatile("s_waitcnt vmcnt(0)" ::: "memory");
    barx();

    for (int t = 0; t < nk; ++t) {
        const int d = t & 1, e = d ^ 1;
        const bool more = (t + 1 < nk);
        {
            s16x8 af[2][4], bf[2][NF];
#pragma unroll
            for (int ks = 0; ks < 2; ++ks) {
                const int csw = ((ks * 4 + lg) ^ (lr & 7)) * 8;
#pragma unroll
                for (int i = 0; i < 4; ++i)
                    af[ks][i] = *(const s16x8*)&As[d][(wm * 128 + i * 16 + lr) * 64 + csw];
#pragma unroll
                for (int j = 0; j < NF; ++j)
                    bf[ks][j] = *(const s16x8*)&Bs[d][(wn * (NF * 16) + j * 16 + lr) * 64 + csw];
            }
            if (more) {
                SA(0, t + 1, e); SA(2, t + 1, e);
#pragma unroll
                for (int u = 0; u < NF; ++u) SB(u, t + 1, e);
            }
            __builtin_amdgcn_s_setprio(1);
#pragma unroll
            for (int ks = 0; ks < 2; ++ks)
#pragma unroll
                for (int i = 0; i < 4; ++i)
#pragma unroll
                    for (int j = 0; j < NF; ++j)
                        acc[i][j] = mfma16(af[ks][i], bf[ks][j], acc[i][j]);
            __builtin_amdgcn_s_setprio(0);
            if (more) { asm volatile("s_waitcnt vmcnt(%0)" :: "i"(NF + 2) : "memory"); }
            else      { asm volatile("s_waitcnt vmcnt(0)" ::: "memory"); }
            barx();
        }
        {
            s16x8 af[2][4], bf[2][NF];
#pragma unroll
            for (int ks = 0; ks < 2; ++ks) {
                const int csw = ((ks * 4 + lg) ^ (lr & 7)) * 8;
#pragma unroll
                for (int i = 0; i < 4; ++i)
                    af[ks][i] = *(const s16x8*)&As[d][(wm * 128 + 64 + i * 16 + lr) * 64 + csw];
#pragma unroll
                for (int j = 0; j < NF; ++j)
                    bf[ks][j] = *(const s16x8*)&Bs[d][(wn * (NF * 16) + j * 16 + lr) * 64 + csw];
            }
            if (more) { SA(1, t + 1, e); SA(3, t + 1, e); }
            __builtin_amdgcn_s_setprio(1);
#pragma unroll
            for (int ks = 0; ks < 2; ++ks)
#pragma unroll
                for (int i = 0; i < 4; ++i)
#pragma unroll
                    for (int j = 0; j < NF; ++j)
                        acc[4 + i][j] = mfma16(af[ks][i], bf[ks][j], acc[4 + i][j]);
            __builtin_amdgcn_s_setprio(0);
            if (more) {
                asm volatile("s_waitcnt vmcnt(2)" ::: "memory");
                barx();
            }
        }
    }
#undef SA
#undef SB

#pragma unroll
    for (int fr = 0; fr < 8; ++fr) {
        const int row = m0 + wm * 128 + fr * 16 + lg * 4;
#pragma unroll
        for (int fc = 0; fc < NF; ++fc) {
            const int col = n0 + wn * (NF * 16) + fc * 16 + lr;
            const float bbv = bias[col];
            if constexpr (OUTBF) {
                short* Cs = (short*)Cv;
#pragma unroll
                for (int r = 0; r < 4; ++r)
                    Cs[(size_t)(row + r) * N + col] = (short)f2bf(acc[fr][fc][r] + bbv);
            } else {
                float* Cf = (float*)Cv;
#pragma unroll
                for (int r = 0; r < 4; ++r)
                    Cf[(size_t)(row + r) * N + col] = acc[fr][fc][r] + bbv;
            }
        }
    }
}

// ---------- rmsnorm + rope + head layout for Q,K (bf16 Y input) ----------
// Q pre-scaled by CS = log2(e)/sqrt(128).
__global__ __launch_bounds__(256) void qkv_post_k(
    const short* __restrict__ Y, const float* __restrict__ qn_w,
    const float* __restrict__ kn_w, const int* __restrict__ start_pos,
    short* __restrict__ Qb, short* __restrict__ Kb) {
    const int m = blockIdx.x;
    const int b = m >> 11, s = m & 2047;
    const short* y = Y + (size_t)m * 3072;
    const int tid = threadIdx.x;
    const float CS = 0.12751745f;

    s16x8 qv = *(const s16x8*)(y + tid * 8);
    float qn[8];
#pragma unroll
    for (int j = 0; j < 8; ++j) qn[j] = bf2f((uint32_t)(unsigned short)qv[j]);
    const uint32_t kvu = *(const uint32_t*)(y + 2048 + tid * 2);
    float k1 = bf2f(kvu & 0xffffu), k2 = bf2f(kvu >> 16);

    float ssq = qn[0]*qn[0] + qn[1]*qn[1] + qn[2]*qn[2] + qn[3]*qn[3]
              + qn[4]*qn[4] + qn[5]*qn[5] + qn[6]*qn[6] + qn[7]*qn[7];
    float ssk = k1 * k1 + k2 * k2;
#pragma unroll
    for (int off = 1; off < 64; off <<= 1) {
        ssq += __shfl_xor(ssq, off);
        ssk += __shfl_xor(ssk, off);
    }
    __shared__ float red[8];
    if ((tid & 63) == 0) { red[tid >> 6] = ssq; red[4 + (tid >> 6)] = ssk; }
    __syncthreads();
    const float tq = red[0] + red[1] + red[2] + red[3];
    const float tk = red[4] + red[5] + red[6] + red[7];
    const float rq = rsqrtf(tq * (1.f / 2048.f) + 1.1920929e-07f) * CS;
    const float rk = rsqrtf(tk * (1.f / 512.f) + 1.1920929e-07f);
    const int pos = start_pos[0] + s;

#pragma unroll
    for (int j = 0; j < 8; ++j) qn[j] *= rq * qn_w[tid * 8 + j];
    const int hq = tid >> 4;
    const int din = (tid * 8) & 127;
    unsigned short ob[8];
#pragma unroll
    for (int j = 0; j < 4; ++j) {
        int tt = (din >> 1) + j;
        float inv = __builtin_exp2f(-0.20762050f * (float)tt);
        float ang = (float)pos * inv;
        float sn, cn;
        __sincosf(ang, &sn, &cn);
        float x1 = qn[2 * j], x2 = qn[2 * j + 1];
        ob[2 * j]     = f2bf(x1 * cn - x2 * sn);
        ob[2 * j + 1] = f2bf(x1 * sn + x2 * cn);
    }
    short* qdst = Qb + (((size_t)(b * 16 + hq) * 2048 + s) * 128 + din);
    uint4 w;
    w.x = (uint32_t)ob[0] | ((uint32_t)ob[1] << 16);
    w.y = (uint32_t)ob[2] | ((uint32_t)ob[3] << 16);
    w.z = (uint32_t)ob[4] | ((uint32_t)ob[5] << 16);
    w.w = (uint32_t)ob[6] | ((uint32_t)ob[7] << 16);
    *(uint4*)qdst = w;

    const int colk = tid * 2;
    const int hk = colk >> 7, dk = colk & 127;
    float kk1 = k1 * rk * kn_w[colk], kk2 = k2 * rk * kn_w[colk + 1];
    {
        int tt = dk >> 1;
        float inv = __builtin_exp2f(-0.20762050f * (float)tt);
        float ang = (float)pos * inv;
        float sn, cn;
        __sincosf(ang, &sn, &cn);
        float r1 = kk1 * cn - kk2 * sn, r2 = kk1 * sn + kk2 * cn;
        short* kdst = Kb + (((size_t)(b * 4 + hk) * 2048 + s) * 128 + dk);
        *(uint32_t*)kdst = (uint32_t)f2bf(r1) | ((uint32_t)f2bf(r2) << 16);
    }
}

// ---------- flash attention v9: 2 blocks/CU (66KB LDS), in-block kv-split ----
// grid (8 bhk, 64 y), block = 512 thr = 2 groups x 4 heads, ONE q-tile
// qt = (y<32)? 63-y : y-32  (co-resident pair sums to ~17 stage-iters/CU).
// n = (qt+2)>>1 kv-tiles; g0 takes [0,nh), g1 takes [nh,n) (nh=(n+1)>>1).
// Single-buffered 32KB staging per group; stage->drain->compute per iter
// (drain covered by the co-resident block). Merge g1 partial at end.
__global__ __launch_bounds__(512, 4) void attn_fwd_k(
    const short* __restrict__ Qb, const short* __restrict__ Kb,
    const short* __restrict__ Vtb, const float* __restrict__ gate_logits,
    short* __restrict__ attnb) {
    const int S = 2048;
    __shared__ short KV[2][16384];     // per-group: K 8192 | V 8192 shorts
    __shared__ float Msm[256], Lsm[256];
    const int tid = threadIdx.x, lane = tid & 63;
    const int wid = tid >> 6;
    const int g = wid >> 2;
    const int hw = wid & 3;
    const int y = blockIdx.y;
    const int qt = (y < 32) ? (63 - y) : (y - 32);
    const int bhk = blockIdx.x;
    const int b = bhk >> 2, hk = bhk & 3;
    const int h = hk * 4 + hw;
    const int n = (qt + 2) >> 1;
    const int nh = (n + 1) >> 1, nl = n - nh;
    const int q0 = qt * 32;
    const int ql = lane & 31, hi = lane >> 5;
    const int qg = q0 + ql;
    const float THR = 11.5416f;        // 8 * log2(e)
    const float gl = gate_logits[h];
    const float gate = 1.f / (1.f + __expf(-gl));

    s16x8 qf[8];
#pragma unroll
    for (int kc = 0; kc < 8; ++kc)
        qf[kc] = *(const s16x8*)(Qb + (((size_t)(b * 16 + h) * S + qg) * 128 + hi * 8) + kc * 16);

    f32x16 ov[4];
#pragma unroll
    for (int dc = 0; dc < 4; ++dc)
#pragma unroll
        for (int r = 0; r < 16; ++r) ov[dc][r] = 0.f;
    float mrun = -3.0e38f, lrun = 0.f;

    const int g256 = tid & 255;
    const short* kg[4]; const short* vg[4]; int lb[4];
#pragma unroll
    for (int i = 0; i < 4; ++i) {
        int oo = (i * 256 + g256) * 8;
        lb[i] = (i * 256 + (g256 & ~63)) * 8;
        {
            int row = oo >> 7, col = oo & 127, ch = col >> 3;
            kg[i] = Kb + ((size_t)bhk * S + row) * 128 + ((ch ^ (row & 7)) << 3);
        }
        {
            int row = oo >> 6, col = oo & 63, ch = col >> 3;
            vg[i] = Vtb + ((size_t)bhk * 128 + row) * S + ((ch ^ (row & 7)) << 3);
        }
    }

#define STAGE_TILE(jj) do {                                                      \
        const int base_ = (jj) * 64;                                             \
        _Pragma("unroll")                                                        \
        for (int i_ = 0; i_ < 4; ++i_)                                           \
            gload_lds16(kg[i_] + (size_t)base_ * 128, &KV[g][lb[i_]]);           \
        _Pragma("unroll")                                                        \
        for (int i_ = 0; i_ < 4; ++i_)                                           \
            gload_lds16(vg[i_] + base_, &KV[g][8192 + lb[i_]]);                  \
    } while (0)

    for (int it = 0; it < nh; ++it) {
        const int j = (g == 0) ? it : (nh + it);
        const bool active = (g == 0) || (it < nl);
        if (it > 0) __syncthreads();              // prior compute done before overwrite
        if (active) STAGE_TILE(j);
        asm volatile("s_waitcnt vmcnt(0)");
        __syncthreads();                          // staging visible
        if (active) {
            const int j0 = j * 64;
            const short* Ks = &KV[g][0];
            const short* Vs = &KV[g][8192];
            const bool have1 = (j0 + 32 <= q0 + 31);
            const bool fsub0 = (j0 + 31 <= q0);
            const bool fsub1 = (j0 + 63 <= q0);
            f32x16 s0, s1;
#pragma unroll
            for (int r = 0; r < 16; ++r) { s0[r] = 0.f; s1[r] = 0.f; }
            __builtin_amdgcn_s_setprio(1);
#pragma unroll
            for (int kc = 0; kc < 8; ++kc) {
                const int c = kc * 2 + hi;
                s16x8 kf0 = *(const s16x8*)&Ks[ql * 128 + ((c ^ (ql & 7)) << 3)];
                s0 = mfma32(kf0, qf[kc], s0);
            }
            if (have1) {
#pragma unroll
                for (int kc = 0; kc < 8; ++kc) {
                    const int c = kc * 2 + hi;
                    const int kr = 32 + ql;
                    s16x8 kf1 = *(const s16x8*)&Ks[kr * 128 + ((c ^ (kr & 7)) << 3)];
                    s1 = mfma32(kf1, qf[kc], s1);
                }
            }
            __builtin_amdgcn_s_setprio(0);
            float p0[16], p1[16];
            if (fsub0) {
#pragma unroll
                for (int r = 0; r < 16; ++r) p0[r] = s0[r];
            } else {
#pragma unroll
                for (int r = 0; r < 16; ++r) {
                    int kvg = j0 + ((r & 3) + 8 * (r >> 2) + 4 * hi);
                    p0[r] = (kvg <= qg) ? s0[r] : -3.0e38f;
                }
            }
            if (have1) {
                if (fsub1) {
#pragma unroll
                    for (int r = 0; r < 16; ++r) p1[r] = s1[r];
                } else {
#pragma unroll
                    for (int r = 0; r < 16; ++r) {
                        int kvg = j0 + 32 + ((r & 3) + 8 * (r >> 2) + 4 * hi);
                        p1[r] = (kvg <= qg) ? s1[r] : -3.0e38f;
                    }
                }
            }
            float a0 = fmaxf(p0[0], p0[1]),  a1 = fmaxf(p0[2], p0[3]);
            float a2 = fmaxf(p0[4], p0[5]),  a3 = fmaxf(p0[6], p0[7]);
            float a4 = fmaxf(p0[8], p0[9]),  a5 = fmaxf(p0[10], p0[11]);
            float a6 = fmaxf(p0[12], p0[13]), a7 = fmaxf(p0[14], p0[15]);
            float pmax = fmaxf(fmaxf(fmaxf(a0, a1), fmaxf(a2, a3)),
                               fmaxf(fmaxf(a4, a5), fmaxf(a6, a7)));
            if (have1) {
                float b0 = fmaxf(p1[0], p1[1]),  b1 = fmaxf(p1[2], p1[3]);
                float b2 = fmaxf(p1[4], p1[5]),  b3 = fmaxf(p1[6], p1[7]);
                float b4 = fmaxf(p1[8], p1[9]),  b5 = fmaxf(p1[10], p1[11]);
                float b6 = fmaxf(p1[12], p1[13]), b7 = fmaxf(p1[14], p1[15]);
                pmax = fmaxf(pmax, fmaxf(fmaxf(fmaxf(b0, b1), fmaxf(b2, b3)),
                                         fmaxf(fmaxf(b4, b5), fmaxf(b6, b7))));
            }
            pmax = cross_max(pmax);
            if (__any(pmax - mrun > THR)) {
                float mnew = fmaxf(mrun, pmax);
                float alpha = __builtin_exp2f(mrun - mnew);
                lrun *= alpha;
#pragma unroll
                for (int r = 0; r < 16; ++r) {
                    int cr = (r & 3) + 8 * (r >> 2) + 4 * hi;
                    float ar = __uint_as_float(
                        (uint32_t)__builtin_amdgcn_ds_bpermute(cr << 2, (int)__float_as_uint(alpha)));
                    ov[0][r] *= ar; ov[1][r] *= ar; ov[2][r] *= ar; ov[3][r] *= ar;
                }
                mrun = mnew;
            }
#pragma unroll
            for (int r = 0; r < 16; ++r) p0[r] = __builtin_exp2f(p0[r] - mrun);
            float ps;
            {
                float t0 = (p0[0] + p0[1]) + (p0[2] + p0[3]);
                float t1 = (p0[4] + p0[5]) + (p0[6] + p0[7]);
                float t2 = (p0[8] + p0[9]) + (p0[10] + p0[11]);
                float t3 = (p0[12] + p0[13]) + (p0[14] + p0[15]);
                ps = (t0 + t1) + (t2 + t3);
            }
            if (have1) {
#pragma unroll
                for (int r = 0; r < 16; ++r) p1[r] = __builtin_exp2f(p1[r] - mrun);
                float t0 = (p1[0] + p1[1]) + (p1[2] + p1[3]);
                float t1 = (p1[4] + p1[5]) + (p1[6] + p1[7]);
                float t2 = (p1[8] + p1[9]) + (p1[10] + p1[11]);
                float t3 = (p1[12] + p1[13]) + (p1[14] + p1[15]);
                ps += (t0 + t1) + (t2 + t3);
            }
            lrun += cross_sum(ps);
            union { uint32_t u[4]; s16x8 v; } f00, f01, f10, f11;
            {
                uint32_t w0 = cvtpk_bf16(p0[0], p0[1]),   w1 = cvtpk_bf16(p0[2], p0[3]);
                uint32_t w2 = cvtpk_bf16(p0[4], p0[5]),   w3 = cvtpk_bf16(p0[6], p0[7]);
                uint32_t w4 = cvtpk_bf16(p0[8], p0[9]),   w5 = cvtpk_bf16(p0[10], p0[11]);
                uint32_t w6 = cvtpk_bf16(p0[12], p0[13]), w7 = cvtpk_bf16(p0[14], p0[15]);
                u32x2 r02 = pl32swap(w0, w2); f00.u[0] = r02[0]; f00.u[2] = r02[1];
                u32x2 r13 = pl32swap(w1, w3); f00.u[1] = r13[0]; f00.u[3] = r13[1];
                u32x2 r46 = pl32swap(w4, w6); f01.u[0] = r46[0]; f01.u[2] = r46[1];
                u32x2 r57 = pl32swap(w5, w7); f01.u[1] = r57[0]; f01.u[3] = r57[1];
            }
            if (have1) {
                uint32_t w0 = cvtpk_bf16(p1[0], p1[1]),   w1 = cvtpk_bf16(p1[2], p1[3]);
                uint32_t w2 = cvtpk_bf16(p1[4], p1[5]),   w3 = cvtpk_bf16(p1[6], p1[7]);
                uint32_t w4 = cvtpk_bf16(p1[8], p1[9]),   w5 = cvtpk_bf16(p1[10], p1[11]);
                uint32_t w6 = cvtpk_bf16(p1[12], p1[13]), w7 = cvtpk_bf16(p1[14], p1[15]);
                u32x2 r02 = pl32swap(w0, w2); f10.u[0] = r02[0]; f10.u[2] = r02[1];
                u32x2 r13 = pl32swap(w1, w3); f10.u[1] = r13[0]; f10.u[3] = r13[1];
                u32x2 r46 = pl32swap(w4, w6); f11.u[0] = r46[0]; f11.u[2] = r46[1];
                u32x2 r57 = pl32swap(w5, w7); f11.u[1] = r57[0]; f11.u[3] = r57[1];
            }
            __builtin_amdgcn_s_setprio(1);
#pragma unroll
            for (int dc = 0; dc < 4; ++dc) {
                const int dd = dc * 32 + ql;
                const int sw = (dd & 7);
                s16x8 v0 = *(const s16x8*)&Vs[dd * 64 + (((hi) ^ sw) << 3)];
                ov[dc] = mfma32(f00.v, v0, ov[dc]);
                s16x8 v1 = *(const s16x8*)&Vs[dd * 64 + (((2 + hi) ^ sw) << 3)];
                ov[dc] = mfma32(f01.v, v1, ov[dc]);
                if (have1) {
                    s16x8 v2 = *(const s16x8*)&Vs[dd * 64 + (((4 + hi) ^ sw) << 3)];
                    ov[dc] = mfma32(f10.v, v2, ov[dc]);
                    s16x8 v3 = *(const s16x8*)&Vs[dd * 64 + (((6 + hi) ^ sw) << 3)];
                    ov[dc] = mfma32(f11.v, v3, ov[dc]);
                }
            }
            __builtin_amdgcn_s_setprio(0);
        }
    }

    // ---- merge: g1 partial -> g0, via dead KV LDS ----
    __syncthreads();                               // all compute reads of KV done
    float* mb = (float*)&KV[0][0];                 // 16384 floats = 64KB
    if (g == 1) {
#pragma unroll
        for (int dc = 0; dc < 4; ++dc)
#pragma unroll
            for (int r = 0; r < 16; ++r)
                mb[hw * 4096 + lane * 64 + dc * 16 + r] = ov[dc][r];
        Msm[hw * 64 + lane] = mrun;
        Lsm[hw * 64 + lane] = lrun;
    }
    __syncthreads();
    if (g == 0) {
        const float m1 = Msm[hw * 64 + lane];
        const float l1 = Lsm[hw * 64 + lane];
        const float mm = fmaxf(mrun, m1);
        const float al0 = __builtin_exp2f(mrun - mm);
        const float al1 = __builtin_exp2f(m1 - mm);
        lrun = lrun * al0 + l1 * al1;
#pragma unroll
        for (int r = 0; r < 16; ++r) {
            int cr = (r & 3) + 8 * (r >> 2) + 4 * hi;
            float a0r = __uint_as_float(
                (uint32_t)__builtin_amdgcn_ds_bpermute(cr << 2, (int)__float_as_uint(al0)));
            float a1r = __uint_as_float(
                (uint32_t)__builtin_amdgcn_ds_bpermute(cr << 2, (int)__float_as_uint(al1)));
#pragma unroll
            for (int dc = 0; dc < 4; ++dc)
                ov[dc][r] = ov[dc][r] * a0r + mb[hw * 4096 + lane * 64 + dc * 16 + r] * a1r;
        }
        const float linv = gate / lrun;
#pragma unroll
        for (int r = 0; r < 16; ++r) {
            int cr = (r & 3) + 8 * (r >> 2) + 4 * hi;
            float sc = __uint_as_float(
                (uint32_t)__builtin_amdgcn_ds_bpermute(cr << 2, (int)__float_as_uint(linv)));
            int qrow = q0 + cr;
            short* orow = attnb + ((size_t)(b * S) + qrow) * 2048 + h * 128 + ql;
#pragma unroll
            for (int dc = 0; dc < 4; ++dc)
                orow[dc * 32] = (short)f2bf(ov[dc][r] * sc);
        }
    }
#undef STAGE_TILE
}

// ---------- launch ----------
extern "C" void kernel_launch(void* const* d_in, const int* in_sizes, int n_in,
                              void* d_out, int out_size, void* d_ws, size_t ws_size,
                              hipStream_t stream) {
    const float* x  = (const float*)d_in[0];
    const float* Wq = (const float*)d_in[1];
    const float* bq = (const float*)d_in[2];
    const float* Wk = (const float*)d_in[3];
    const float* bk = (const float*)d_in[4];
    const float* Wv = (const float*)d_in[5];
    const float* bv = (const float*)d_in[6];
    const float* Wo = (const float*)d_in[7];
    const float* bo = (const float*)d_in[8];
    const float* qn = (const float*)d_in[9];
    const float* kn = (const float*)d_in[10];
    const float* gl = (const float*)d_in[11];
    const int* sp   = (const int*)d_in[13];
    float* out = (float*)d_out;

    char* ws = (char*)d_ws;
    const size_t NEED = 96481280;
    if (ws_size < NEED) return;
    short* xb    = (short*)(ws + 0);            // 16 MiB, reused as Qb
    short* wqkvT = (short*)(ws + 16777216);     // 12 MiB
    short* woT   = (short*)(ws + 29360128);     // 8 MiB
    float* bqkv  = (float*)(ws + 37748736);     // 12 KiB
    short* Yb    = (short*)(ws + 37761024);     // 24 MiB bf16, head reused as attnb
    short* Kb    = (short*)(ws + 88092672);     // 4 MiB
    short* Vtb   = (short*)(ws + 92286976);     // 4 MiB
    short* Qb    = xb;
    short* attnb = Yb;

    f32_to_bf16_k<<<4096, 256, 0, stream>>>(x, xb, 1048576);
    transpose_f32_bf16_k<<<dim3(32, 32, 1), 256, 0, stream>>>(Wq, 0, 2048, wqkvT, 0, 2048);
    transpose_f32_bf16_k<<<dim3(8, 32, 1), 256, 0, stream>>>(Wk, 0, 512, wqkvT + (size_t)2048 * 2048, 0, 2048);
    transpose_f32_bf16_k<<<dim3(8, 32, 1), 256, 0, stream>>>(Wv, 0, 512, wqkvT + (size_t)2560 * 2048, 0, 2048);
    transpose_f32_bf16_k<<<dim3(32, 32, 1), 256, 0, stream>>>(Wo, 0, 2048, woT, 0, 2048);
    concat_bias_k<<<12, 256, 0, stream>>>(bq, bk, bv, bqkv);
    gemm256_k<0, true, 3><<<dim3(16, 16), 512, 0, stream>>>(xb, wqkvT, bqkv, Yb, 4096, 3072, 2048);
    qkv_post_k<<<4096, 256, 0, stream>>>(Yb, qn, kn, sp, Qb, Kb);
    transpose_bf16_k<<<dim3(8, 32, 2), 256, 0, stream>>>(
        Yb + 2560, (size_t)2048 * 3072, 3072, Vtb, (size_t)512 * 2048, 2048);
    attn_fwd_k<<<dim3(8, 64), 512, 0, stream>>>(Qb, Kb, Vtb, gl, attnb);
    gemm256_k<1, false, 2><<<dim3(16, 16), 512, 0, stream>>>(attnb, woT, bo, out, 4096, 2048, 2048);
}

// Round 20
// 217.114 us; speedup vs baseline: 1.4699x; 1.4699x over previous
//
#include <hip/hip_runtime.h>
#include <hip/hip_bf16.h>
#include <stdint.h>

#define DEV __device__ __forceinline__

typedef short     s16x8  __attribute__((ext_vector_type(8)));
typedef __bf16    bf16v8 __attribute__((ext_vector_type(8)));
typedef float     f32x4  __attribute__((ext_vector_type(4)));
typedef float     f32x16 __attribute__((ext_vector_type(16)));
typedef unsigned int u32x2 __attribute__((ext_vector_type(2)));

// ---------- helpers ----------
DEV unsigned short f2bf(float x) {
    uint32_t u = __float_as_uint(x);
    uint32_t r = (u + 0x7FFFu + ((u >> 16) & 1u)) >> 16;
    return (unsigned short)r;
}
DEV float bf2f(uint32_t u) { return __uint_as_float(u << 16); }

DEV void gload_lds16(const void* g, void* l) {
    __builtin_amdgcn_global_load_lds((const __attribute__((address_space(1))) void*)g,
                                     (__attribute__((address_space(3))) void*)l,
                                     16, 0, 0);
}

DEV f32x4 mfma16(s16x8 a, s16x8 b, f32x4 c) {
    return __builtin_amdgcn_mfma_f32_16x16x32_bf16(
        __builtin_bit_cast(bf16v8, a), __builtin_bit_cast(bf16v8, b), c, 0, 0, 0);
}
DEV f32x16 mfma32(s16x8 a, s16x8 b, f32x16 c) {
    return __builtin_amdgcn_mfma_f32_32x32x16_bf16(
        __builtin_bit_cast(bf16v8, a), __builtin_bit_cast(bf16v8, b), c, 0, 0, 0);
}

DEV uint32_t cvtpk_bf16(float lo, float hi) {
    uint32_t r;
    asm volatile("v_cvt_pk_bf16_f32 %0, %1, %2" : "=v"(r) : "v"(lo), "v"(hi));
    return r;
}

DEV u32x2 pl32swap(uint32_t a, uint32_t b) {
    return __builtin_amdgcn_permlane32_swap(a, b, false, false);
}
DEV float cross_max(float x) {
    u32x2 r = pl32swap(__float_as_uint(x), __float_as_uint(x));
    return fmaxf(__uint_as_float(r[0]), __uint_as_float(r[1]));
}
DEV float cross_sum(float x) {
    u32x2 r = pl32swap(__float_as_uint(x), __float_as_uint(x));
    return __uint_as_float(r[0]) + __uint_as_float(r[1]);
}

DEV void barx() {
    asm volatile("" ::: "memory");
    __builtin_amdgcn_s_barrier();
    __builtin_amdgcn_sched_barrier(0);
    asm volatile("" ::: "memory");
}

// ---------- elementwise f32 -> bf16 ----------
__global__ void f32_to_bf16_k(const float* __restrict__ in, short* __restrict__ out, int n8) {
    int i = blockIdx.x * blockDim.x + threadIdx.x;
    if (i >= n8) return;
    const float4 a = *(const float4*)(in + (size_t)i * 8);
    const float4 b = *(const float4*)(in + (size_t)i * 8 + 4);
    uint4 w;
    w.x = (uint32_t)f2bf(a.x) | ((uint32_t)f2bf(a.y) << 16);
    w.y = (uint32_t)f2bf(a.z) | ((uint32_t)f2bf(a.w) << 16);
    w.z = (uint32_t)f2bf(b.x) | ((uint32_t)f2bf(b.y) << 16);
    w.w = (uint32_t)f2bf(b.z) | ((uint32_t)f2bf(b.w) << 16);
    *(uint4*)(out + (size_t)i * 8) = w;
}

// ---------- tiled transpose f32 (R x C) -> bf16 (C x R) ----------
__global__ __launch_bounds__(256) void transpose_f32_bf16_k(
    const float* __restrict__ in, size_t in_batch, int ld_in,
    short* __restrict__ out, size_t out_batch, int ld_out) {
    __shared__ float tile[64][65];
    const float* ip = in + (size_t)blockIdx.z * in_batch;
    short* op = out + (size_t)blockIdx.z * out_batch;
    const int c0 = blockIdx.x * 64, r0 = blockIdx.y * 64;
    const int t = threadIdx.x;
    const int cc4 = (t & 15) * 4;
    const int rr  = t >> 4;
#pragma unroll
    for (int p = 0; p < 4; ++p) {
        int r = rr + p * 16;
        float4 v = *(const float4*)(ip + (size_t)(r0 + r) * ld_in + c0 + cc4);
        tile[r][cc4 + 0] = v.x; tile[r][cc4 + 1] = v.y;
        tile[r][cc4 + 2] = v.z; tile[r][cc4 + 3] = v.w;
    }
    __syncthreads();
#pragma unroll
    for (int p = 0; p < 4; ++p) {
        int oc  = (t >> 4) + p * 16;
        int rr4 = (t & 15) * 4;
        ushort4 w;
        w.x = f2bf(tile[rr4 + 0][oc]);
        w.y = f2bf(tile[rr4 + 1][oc]);
        w.z = f2bf(tile[rr4 + 2][oc]);
        w.w = f2bf(tile[rr4 + 3][oc]);
        *(ushort4*)(op + (size_t)(c0 + oc) * ld_out + r0 + rr4) = w;
    }
}

// ---------- tiled transpose bf16 (R x C) -> bf16 (C x R) ----------
__global__ __launch_bounds__(256) void transpose_bf16_k(
    const short* __restrict__ in, size_t in_batch, int ld_in,
    short* __restrict__ out, size_t out_batch, int ld_out) {
    __shared__ short tile[64][72];
    const short* ip = in + (size_t)blockIdx.z * in_batch;
    short* op = out + (size_t)blockIdx.z * out_batch;
    const int c0 = blockIdx.x * 64, r0 = blockIdx.y * 64;
    const int t = threadIdx.x;
    const int cc = (t & 7) * 8;
    const int rr = t >> 3;
#pragma unroll
    for (int p = 0; p < 2; ++p) {
        int r = rr + p * 32;
        s16x8 v = *(const s16x8*)(ip + (size_t)(r0 + r) * ld_in + c0 + cc);
        *(s16x8*)&tile[r][cc] = v;
    }
    __syncthreads();
    const int oc = t >> 2;
    const int rb = (t & 3) * 16;
    s16x8 w0, w1;
#pragma unroll
    for (int j = 0; j < 8; ++j) w0[j] = tile[rb + j][oc];
#pragma unroll
    for (int j = 0; j < 8; ++j) w1[j] = tile[rb + 8 + j][oc];
    *(s16x8*)(op + (size_t)(c0 + oc) * ld_out + r0 + rb) = w0;
    *(s16x8*)(op + (size_t)(c0 + oc) * ld_out + r0 + rb + 8) = w1;
}

// ---------- bias concat ----------
__global__ void concat_bias_k(const float* __restrict__ bq, const float* __restrict__ bk,
                              const float* __restrict__ bv, float* __restrict__ o) {
    int i = blockIdx.x * 256 + threadIdx.x;
    if (i < 2048)       o[i] = bq[i];
    else if (i < 2560)  o[i] = bk[i - 2048];
    else if (i < 3072)  o[i] = bv[i - 2560];
}

// ---------- GEMM v5 (r12-proven): 2-phase counted-vmcnt ----------
template<int TAG, bool OUTBF, int NF>
__global__ __launch_bounds__(512, 2) void gemm256_k(
    const short* __restrict__ A, const short* __restrict__ Bt,
    const float* __restrict__ bias, void* __restrict__ Cv,
    int M, int N, int K) {
    __shared__ short As[2][16384];
    __shared__ short Bs[2][NF * 4096];
    const int tid = threadIdx.x;
    const int gx = gridDim.x;
    const int nwg = gx * gridDim.y;
    const int flat = blockIdx.y * gx + blockIdx.x;
    const int cpx = nwg >> 3;
    const int swz = (flat & 7) * cpx + (flat >> 3);
    const int m0 = (swz / gx) * 256, n0 = (swz % gx) * (NF * 64);
    const int lane = tid & 63, wid = tid >> 6;
    const int wm = wid >> 2, wn = wid & 3;
    const int lr = lane & 15, lg = lane >> 4;

    const int srow = tid >> 3;
    const int schunk = ((tid & 7) ^ (srow & 7)) << 3;
    const short* Ag = A  + (size_t)(m0 + srow) * K + schunk;
    const short* Bg = Bt + (size_t)(n0 + srow) * K + schunk;
    const int lwb = (tid & ~63) * 8;

    f32x4 acc[8][NF];
#pragma unroll
    for (int fr = 0; fr < 8; ++fr)
#pragma unroll
        for (int fc = 0; fc < NF; ++fc)
#pragma unroll
            for (int r = 0; r < 4; ++r) acc[fr][fc][r] = 0.f;

    const int nk = K >> 6;

#define SA(u, kt, dd) gload_lds16(Ag + (size_t)(u) * 64 * K + (kt) * 64, &As[dd][(u) * 4096 + lwb])
#define SB(u, kt, dd) gload_lds16(Bg + (size_t)(u) * 64 * K + (kt) * 64, &Bs[dd][(u) * 4096 + lwb])

    SA(0, 0, 0); SA(1, 0, 0); SA(2, 0, 0); SA(3, 0, 0);
#pragma unroll
    for (int u = 0; u < NF; ++u) SB(u, 0, 0);
    asm volatile("s_waitcnt vmcnt(0)" ::: "memory");
    barx();

    for (int t = 0; t < nk; ++t) {
        const int d = t & 1, e = d ^ 1;
        const bool more = (t + 1 < nk);
        {
            s16x8 af[2][4], bf[2][NF];
#pragma unroll
            for (int ks = 0; ks < 2; ++ks) {
                const int csw = ((ks * 4 + lg) ^ (lr & 7)) * 8;
#pragma unroll
                for (int i = 0; i < 4; ++i)
                    af[ks][i] = *(const s16x8*)&As[d][(wm * 128 + i * 16 + lr) * 64 + csw];
#pragma unroll
                for (int j = 0; j < NF; ++j)
                    bf[ks][j] = *(const s16x8*)&Bs[d][(wn * (NF * 16) + j * 16 + lr) * 64 + csw];
            }
            if (more) {
                SA(0, t + 1, e); SA(2, t + 1, e);
#pragma unroll
                for (int u = 0; u < NF; ++u) SB(u, t + 1, e);
            }
            __builtin_amdgcn_s_setprio(1);
#pragma unroll
            for (int ks = 0; ks < 2; ++ks)
#pragma unroll
                for (int i = 0; i < 4; ++i)
#pragma unroll
                    for (int j = 0; j < NF; ++j)
                        acc[i][j] = mfma16(af[ks][i], bf[ks][j], acc[i][j]);
            __builtin_amdgcn_s_setprio(0);
            if (more) { asm volatile("s_waitcnt vmcnt(%0)" :: "i"(NF + 2) : "memory"); }
            else      { asm volatile("s_waitcnt vmcnt(0)" ::: "memory"); }
            barx();
        }
        {
            s16x8 af[2][4], bf[2][NF];
#pragma unroll
            for (int ks = 0; ks < 2; ++ks) {
                const int csw = ((ks * 4 + lg) ^ (lr & 7)) * 8;
#pragma unroll
                for (int i = 0; i < 4; ++i)
                    af[ks][i] = *(const s16x8*)&As[d][(wm * 128 + 64 + i * 16 + lr) * 64 + csw];
#pragma unroll
                for (int j = 0; j < NF; ++j)
                    bf[ks][j] = *(const s16x8*)&Bs[d][(wn * (NF * 16) + j * 16 + lr) * 64 + csw];
            }
            if (more) { SA(1, t + 1, e); SA(3, t + 1, e); }
            __builtin_amdgcn_s_setprio(1);
#pragma unroll
            for (int ks = 0; ks < 2; ++ks)
#pragma unroll
                for (int i = 0; i < 4; ++i)
#pragma unroll
                    for (int j = 0; j < NF; ++j)
                        acc[4 + i][j] = mfma16(af[ks][i], bf[ks][j], acc[4 + i][j]);
            __builtin_amdgcn_s_setprio(0);
            if (more) {
                asm volatile("s_waitcnt vmcnt(2)" ::: "memory");
                barx();
            }
        }
    }
#undef SA
#undef SB

#pragma unroll
    for (int fr = 0; fr < 8; ++fr) {
        const int row = m0 + wm * 128 + fr * 16 + lg * 4;
#pragma unroll
        for (int fc = 0; fc < NF; ++fc) {
            const int col = n0 + wn * (NF * 16) + fc * 16 + lr;
            const float bbv = bias[col];
            if constexpr (OUTBF) {
                short* Cs = (short*)Cv;
#pragma unroll
                for (int r = 0; r < 4; ++r)
                    Cs[(size_t)(row + r) * N + col] = (short)f2bf(acc[fr][fc][r] + bbv);
            } else {
                float* Cf = (float*)Cv;
#pragma unroll
                for (int r = 0; r < 4; ++r)
                    Cf[(size_t)(row + r) * N + col] = acc[fr][fc][r] + bbv;
            }
        }
    }
}

// ---------- rmsnorm + rope + head layout for Q,K (bf16 Y input) ----------
// Q pre-scaled by CS = log2(e)/sqrt(128).
__global__ __launch_bounds__(256) void qkv_post_k(
    const short* __restrict__ Y, const float* __restrict__ qn_w,
    const float* __restrict__ kn_w, const int* __restrict__ start_pos,
    short* __restrict__ Qb, short* __restrict__ Kb) {
    const int m = blockIdx.x;
    const int b = m >> 11, s = m & 2047;
    const short* y = Y + (size_t)m * 3072;
    const int tid = threadIdx.x;
    const float CS = 0.12751745f;

    s16x8 qv = *(const s16x8*)(y + tid * 8);
    float qn[8];
#pragma unroll
    for (int j = 0; j < 8; ++j) qn[j] = bf2f((uint32_t)(unsigned short)qv[j]);
    const uint32_t kvu = *(const uint32_t*)(y + 2048 + tid * 2);
    float k1 = bf2f(kvu & 0xffffu), k2 = bf2f(kvu >> 16);

    float ssq = qn[0]*qn[0] + qn[1]*qn[1] + qn[2]*qn[2] + qn[3]*qn[3]
              + qn[4]*qn[4] + qn[5]*qn[5] + qn[6]*qn[6] + qn[7]*qn[7];
    float ssk = k1 * k1 + k2 * k2;
#pragma unroll
    for (int off = 1; off < 64; off <<= 1) {
        ssq += __shfl_xor(ssq, off);
        ssk += __shfl_xor(ssk, off);
    }
    __shared__ float red[8];
    if ((tid & 63) == 0) { red[tid >> 6] = ssq; red[4 + (tid >> 6)] = ssk; }
    __syncthreads();
    const float tq = red[0] + red[1] + red[2] + red[3];
    const float tk = red[4] + red[5] + red[6] + red[7];
    const float rq = rsqrtf(tq * (1.f / 2048.f) + 1.1920929e-07f) * CS;
    const float rk = rsqrtf(tk * (1.f / 512.f) + 1.1920929e-07f);
    const int pos = start_pos[0] + s;

#pragma unroll
    for (int j = 0; j < 8; ++j) qn[j] *= rq * qn_w[tid * 8 + j];
    const int hq = tid >> 4;
    const int din = (tid * 8) & 127;
    unsigned short ob[8];
#pragma unroll
    for (int j = 0; j < 4; ++j) {
        int tt = (din >> 1) + j;
        float inv = __builtin_exp2f(-0.20762050f * (float)tt);
        float ang = (float)pos * inv;
        float sn, cn;
        __sincosf(ang, &sn, &cn);
        float x1 = qn[2 * j], x2 = qn[2 * j + 1];
        ob[2 * j]     = f2bf(x1 * cn - x2 * sn);
        ob[2 * j + 1] = f2bf(x1 * sn + x2 * cn);
    }
    short* qdst = Qb + (((size_t)(b * 16 + hq) * 2048 + s) * 128 + din);
    uint4 w;
    w.x = (uint32_t)ob[0] | ((uint32_t)ob[1] << 16);
    w.y = (uint32_t)ob[2] | ((uint32_t)ob[3] << 16);
    w.z = (uint32_t)ob[4] | ((uint32_t)ob[5] << 16);
    w.w = (uint32_t)ob[6] | ((uint32_t)ob[7] << 16);
    *(uint4*)qdst = w;

    const int colk = tid * 2;
    const int hk = colk >> 7, dk = colk & 127;
    float kk1 = k1 * rk * kn_w[colk], kk2 = k2 * rk * kn_w[colk + 1];
    {
        int tt = dk >> 1;
        float inv = __builtin_exp2f(-0.20762050f * (float)tt);
        float ang = (float)pos * inv;
        float sn, cn;
        __sincosf(ang, &sn, &cn);
        float r1 = kk1 * cn - kk2 * sn, r2 = kk1 * sn + kk2 * cn;
        short* kdst = Kb + (((size_t)(b * 4 + hk) * 2048 + s) * 128 + dk);
        *(uint32_t*)kdst = (uint32_t)f2bf(r1) | ((uint32_t)f2bf(r2) << 16);
    }
}

// ---------- flash attention v9b: r15's epoch-validated single-buffer
// structure, launch bound relaxed (512,1) to remove the r15 spill (VGPR
// cap 64 -> scratch). grid (8 bhk, 64 y), block = 512 thr = 2 groups x 4
// heads, ONE q-tile qt = (y<32)? 63-y : y-32. n = (qt+2)>>1 kv-tiles;
// g0 takes [0,nh), g1 takes [nh,n). stage->drain->compute per iter.
__global__ __launch_bounds__(512, 1) void attn_fwd_k(
    const short* __restrict__ Qb, const short* __restrict__ Kb,
    const short* __restrict__ Vtb, const float* __restrict__ gate_logits,
    short* __restrict__ attnb) {
    const int S = 2048;
    __shared__ short KV[2][16384];     // per-group: K 8192 | V 8192 shorts
    __shared__ float Msm[256], Lsm[256];
    const int tid = threadIdx.x, lane = tid & 63;
    const int wid = tid >> 6;
    const int g = wid >> 2;
    const int hw = wid & 3;
    const int y = blockIdx.y;
    const int qt = (y < 32) ? (63 - y) : (y - 32);
    const int bhk = blockIdx.x;
    const int b = bhk >> 2, hk = bhk & 3;
    const int h = hk * 4 + hw;
    const int n = (qt + 2) >> 1;
    const int nh = (n + 1) >> 1, nl = n - nh;
    const int q0 = qt * 32;
    const int ql = lane & 31, hi = lane >> 5;
    const int qg = q0 + ql;
    const float THR = 11.5416f;        // 8 * log2(e)
    const float gl = gate_logits[h];
    const float gate = 1.f / (1.f + __expf(-gl));

    s16x8 qf[8];
#pragma unroll
    for (int kc = 0; kc < 8; ++kc)
        qf[kc] = *(const s16x8*)(Qb + (((size_t)(b * 16 + h) * S + qg) * 128 + hi * 8) + kc * 16);

    f32x16 ov[4];
#pragma unroll
    for (int dc = 0; dc < 4; ++dc)
#pragma unroll
        for (int r = 0; r < 16; ++r) ov[dc][r] = 0.f;
    float mrun = -3.0e38f, lrun = 0.f;

    const int g256 = tid & 255;
    const short* kg[4]; const short* vg[4]; int lb[4];
#pragma unroll
    for (int i = 0; i < 4; ++i) {
        int oo = (i * 256 + g256) * 8;
        lb[i] = (i * 256 + (g256 & ~63)) * 8;
        {
            int row = oo >> 7, col = oo & 127, ch = col >> 3;
            kg[i] = Kb + ((size_t)bhk * S + row) * 128 + ((ch ^ (row & 7)) << 3);
        }
        {
            int row = oo >> 6, col = oo & 63, ch = col >> 3;
            vg[i] = Vtb + ((size_t)bhk * 128 + row) * S + ((ch ^ (row & 7)) << 3);
        }
    }

#define STAGE_TILE(jj) do {                                                      \
        const int base_ = (jj) * 64;                                             \
        _Pragma("unroll")                                                        \
        for (int i_ = 0; i_ < 4; ++i_)                                           \
            gload_lds16(kg[i_] + (size_t)base_ * 128, &KV[g][lb[i_]]);           \
        _Pragma("unroll")                                                        \
        for (int i_ = 0; i_ < 4; ++i_)                                           \
            gload_lds16(vg[i_] + base_, &KV[g][8192 + lb[i_]]);                  \
    } while (0)

    for (int it = 0; it < nh; ++it) {
        const int j = (g == 0) ? it : (nh + it);
        const bool active = (g == 0) || (it < nl);
        if (it > 0) __syncthreads();              // prior compute done before overwrite
        if (active) STAGE_TILE(j);
        asm volatile("s_waitcnt vmcnt(0)");
        __syncthreads();                          // staging visible
        if (active) {
            const int j0 = j * 64;
            const short* Ks = &KV[g][0];
            const short* Vs = &KV[g][8192];
            const bool have1 = (j0 + 32 <= q0 + 31);
            const bool fsub0 = (j0 + 31 <= q0);
            const bool fsub1 = (j0 + 63 <= q0);
            f32x16 s0, s1;
#pragma unroll
            for (int r = 0; r < 16; ++r) { s0[r] = 0.f; s1[r] = 0.f; }
            __builtin_amdgcn_s_setprio(1);
#pragma unroll
            for (int kc = 0; kc < 8; ++kc) {
                const int c = kc * 2 + hi;
                s16x8 kf0 = *(const s16x8*)&Ks[ql * 128 + ((c ^ (ql & 7)) << 3)];
                s0 = mfma32(kf0, qf[kc], s0);
            }
            if (have1) {
#pragma unroll
                for (int kc = 0; kc < 8; ++kc) {
                    const int c = kc * 2 + hi;
                    const int kr = 32 + ql;
                    s16x8 kf1 = *(const s16x8*)&Ks[kr * 128 + ((c ^ (kr & 7)) << 3)];
                    s1 = mfma32(kf1, qf[kc], s1);
                }
            }
            __builtin_amdgcn_s_setprio(0);
            float p0[16], p1[16];
            if (fsub0) {
#pragma unroll
                for (int r = 0; r < 16; ++r) p0[r] = s0[r];
            } else {
#pragma unroll
                for (int r = 0; r < 16; ++r) {
                    int kvg = j0 + ((r & 3) + 8 * (r >> 2) + 4 * hi);
                    p0[r] = (kvg <= qg) ? s0[r] : -3.0e38f;
                }
            }
            if (have1) {
                if (fsub1) {
#pragma unroll
                    for (int r = 0; r < 16; ++r) p1[r] = s1[r];
                } else {
#pragma unroll
                    for (int r = 0; r < 16; ++r) {
                        int kvg = j0 + 32 + ((r & 3) + 8 * (r >> 2) + 4 * hi);
                        p1[r] = (kvg <= qg) ? s1[r] : -3.0e38f;
                    }
                }
            }
            float a0 = fmaxf(p0[0], p0[1]),  a1 = fmaxf(p0[2], p0[3]);
            float a2 = fmaxf(p0[4], p0[5]),  a3 = fmaxf(p0[6], p0[7]);
            float a4 = fmaxf(p0[8], p0[9]),  a5 = fmaxf(p0[10], p0[11]);
            float a6 = fmaxf(p0[12], p0[13]), a7 = fmaxf(p0[14], p0[15]);
            float pmax = fmaxf(fmaxf(fmaxf(a0, a1), fmaxf(a2, a3)),
                               fmaxf(fmaxf(a4, a5), fmaxf(a6, a7)));
            if (have1) {
                float b0 = fmaxf(p1[0], p1[1]),  b1 = fmaxf(p1[2], p1[3]);
                float b2 = fmaxf(p1[4], p1[5]),  b3 = fmaxf(p1[6], p1[7]);
                float b4 = fmaxf(p1[8], p1[9]),  b5 = fmaxf(p1[10], p1[11]);
                float b6 = fmaxf(p1[12], p1[13]), b7 = fmaxf(p1[14], p1[15]);
                pmax = fmaxf(pmax, fmaxf(fmaxf(fmaxf(b0, b1), fmaxf(b2, b3)),
                                         fmaxf(fmaxf(b4, b5), fmaxf(b6, b7))));
            }
            pmax = cross_max(pmax);
            if (__any(pmax - mrun > THR)) {
                float mnew = fmaxf(mrun, pmax);
                float alpha = __builtin_exp2f(mrun - mnew);
                lrun *= alpha;
#pragma unroll
                for (int r = 0; r < 16; ++r) {
                    int cr = (r & 3) + 8 * (r >> 2) + 4 * hi;
                    float ar = __uint_as_float(
                        (uint32_t)__builtin_amdgcn_ds_bpermute(cr << 2, (int)__float_as_uint(alpha)));
                    ov[0][r] *= ar; ov[1][r] *= ar; ov[2][r] *= ar; ov[3][r] *= ar;
                }
                mrun = mnew;
            }
#pragma unroll
            for (int r = 0; r < 16; ++r) p0[r] = __builtin_exp2f(p0[r] - mrun);
            float ps;
            {
                float t0 = (p0[0] + p0[1]) + (p0[2] + p0[3]);
                float t1 = (p0[4] + p0[5]) + (p0[6] + p0[7]);
                float t2 = (p0[8] + p0[9]) + (p0[10] + p0[11]);
                float t3 = (p0[12] + p0[13]) + (p0[14] + p0[15]);
                ps = (t0 + t1) + (t2 + t3);
            }
            if (have1) {
#pragma unroll
                for (int r = 0; r < 16; ++r) p1[r] = __builtin_exp2f(p1[r] - mrun);
                float t0 = (p1[0] + p1[1]) + (p1[2] + p1[3]);
                float t1 = (p1[4] + p1[5]) + (p1[6] + p1[7]);
                float t2 = (p1[8] + p1[9]) + (p1[10] + p1[11]);
                float t3 = (p1[12] + p1[13]) + (p1[14] + p1[15]);
                ps += (t0 + t1) + (t2 + t3);
            }
            lrun += cross_sum(ps);
            union { uint32_t u[4]; s16x8 v; } f00, f01, f10, f11;
            {
                uint32_t w0 = cvtpk_bf16(p0[0], p0[1]),   w1 = cvtpk_bf16(p0[2], p0[3]);
                uint32_t w2 = cvtpk_bf16(p0[4], p0[5]),   w3 = cvtpk_bf16(p0[6], p0[7]);
                uint32_t w4 = cvtpk_bf16(p0[8], p0[9]),   w5 = cvtpk_bf16(p0[10], p0[11]);
                uint32_t w6 = cvtpk_bf16(p0[12], p0[13]), w7 = cvtpk_bf16(p0[14], p0[15]);
                u32x2 r02 = pl32swap(w0, w2); f00.u[0] = r02[0]; f00.u[2] = r02[1];
                u32x2 r13 = pl32swap(w1, w3); f00.u[1] = r13[0]; f00.u[3] = r13[1];
                u32x2 r46 = pl32swap(w4, w6); f01.u[0] = r46[0]; f01.u[2] = r46[1];
                u32x2 r57 = pl32swap(w5, w7); f01.u[1] = r57[0]; f01.u[3] = r57[1];
            }
            if (have1) {
                uint32_t w0 = cvtpk_bf16(p1[0], p1[1]),   w1 = cvtpk_bf16(p1[2], p1[3]);
                uint32_t w2 = cvtpk_bf16(p1[4], p1[5]),   w3 = cvtpk_bf16(p1[6], p1[7]);
                uint32_t w4 = cvtpk_bf16(p1[8], p1[9]),   w5 = cvtpk_bf16(p1[10], p1[11]);
                uint32_t w6 = cvtpk_bf16(p1[12], p1[13]), w7 = cvtpk_bf16(p1[14], p1[15]);
                u32x2 r02 = pl32swap(w0, w2); f10.u[0] = r02[0]; f10.u[2] = r02[1];
                u32x2 r13 = pl32swap(w1, w3); f10.u[1] = r13[0]; f10.u[3] = r13[1];
                u32x2 r46 = pl32swap(w4, w6); f11.u[0] = r46[0]; f11.u[2] = r46[1];
                u32x2 r57 = pl32swap(w5, w7); f11.u[1] = r57[0]; f11.u[3] = r57[1];
            }
            __builtin_amdgcn_s_setprio(1);
#pragma unroll
            for (int dc = 0; dc < 4; ++dc) {
                const int dd = dc * 32 + ql;
                const int sw = (dd & 7);
                s16x8 v0 = *(const s16x8*)&Vs[dd * 64 + (((hi) ^ sw) << 3)];
                ov[dc] = mfma32(f00.v, v0, ov[dc]);
                s16x8 v1 = *(const s16x8*)&Vs[dd * 64 + (((2 + hi) ^ sw) << 3)];
                ov[dc] = mfma32(f01.v, v1, ov[dc]);
                if (have1) {
                    s16x8 v2 = *(const s16x8*)&Vs[dd * 64 + (((4 + hi) ^ sw) << 3)];
                    ov[dc] = mfma32(f10.v, v2, ov[dc]);
                    s16x8 v3 = *(const s16x8*)&Vs[dd * 64 + (((6 + hi) ^ sw) << 3)];
                    ov[dc] = mfma32(f11.v, v3, ov[dc]);
                }
            }
            __builtin_amdgcn_s_setprio(0);
        }
    }

    // ---- merge: g1 partial -> g0, via dead KV LDS ----
    __syncthreads();                               // all compute reads of KV done
    float* mb = (float*)&KV[0][0];                 // 16384 floats = 64KB
    if (g == 1) {
#pragma unroll
        for (int dc = 0; dc < 4; ++dc)
#pragma unroll
            for (int r = 0; r < 16; ++r)
                mb[hw * 4096 + lane * 64 + dc * 16 + r] = ov[dc][r];
        Msm[hw * 64 + lane] = mrun;
        Lsm[hw * 64 + lane] = lrun;
    }
    __syncthreads();
    if (g == 0) {
        const float m1 = Msm[hw * 64 + lane];
        const float l1 = Lsm[hw * 64 + lane];
        const float mm = fmaxf(mrun, m1);
        const float al0 = __builtin_exp2f(mrun - mm);
        const float al1 = __builtin_exp2f(m1 - mm);
        lrun = lrun * al0 + l1 * al1;
#pragma unroll
        for (int r = 0; r < 16; ++r) {
            int cr = (r & 3) + 8 * (r >> 2) + 4 * hi;
            float a0r = __uint_as_float(
                (uint32_t)__builtin_amdgcn_ds_bpermute(cr << 2, (int)__float_as_uint(al0)));
            float a1r = __uint_as_float(
                (uint32_t)__builtin_amdgcn_ds_bpermute(cr << 2, (int)__float_as_uint(al1)));
#pragma unroll
            for (int dc = 0; dc < 4; ++dc)
                ov[dc][r] = ov[dc][r] * a0r + mb[hw * 4096 + lane * 64 + dc * 16 + r] * a1r;
        }
        const float linv = gate / lrun;
#pragma unroll
        for (int r = 0; r < 16; ++r) {
            int cr = (r & 3) + 8 * (r >> 2) + 4 * hi;
            float sc = __uint_as_float(
                (uint32_t)__builtin_amdgcn_ds_bpermute(cr << 2, (int)__float_as_uint(linv)));
            int qrow = q0 + cr;
            short* orow = attnb + ((size_t)(b * S) + qrow) * 2048 + h * 128 + ql;
#pragma unroll
            for (int dc = 0; dc < 4; ++dc)
                orow[dc * 32] = (short)f2bf(ov[dc][r] * sc);
        }
    }
#undef STAGE_TILE
}

// ---------- launch ----------
extern "C" void kernel_launch(void* const* d_in, const int* in_sizes, int n_in,
                              void* d_out, int out_size, void* d_ws, size_t ws_size,
                              hipStream_t stream) {
    const float* x  = (const float*)d_in[0];
    const float* Wq = (const float*)d_in[1];
    const float* bq = (const float*)d_in[2];
    const float* Wk = (const float*)d_in[3];
    const float* bk = (const float*)d_in[4];
    const float* Wv = (const float*)d_in[5];
    const float* bv = (const float*)d_in[6];
    const float* Wo = (const float*)d_in[7];
    const float* bo = (const float*)d_in[8];
    const float* qn = (const float*)d_in[9];
    const float* kn = (const float*)d_in[10];
    const float* gl = (const float*)d_in[11];
    const int* sp   = (const int*)d_in[13];
    float* out = (float*)d_out;

    char* ws = (char*)d_ws;
    const size_t NEED = 96481280;
    if (ws_size < NEED) return;
    short* xb    = (short*)(ws + 0);            // 16 MiB, reused as Qb
    short* wqkvT = (short*)(ws + 16777216);     // 12 MiB
    short* woT   = (short*)(ws + 29360128);     // 8 MiB
    float* bqkv  = (float*)(ws + 37748736);     // 12 KiB
    short* Yb    = (short*)(ws + 37761024);     // 24 MiB bf16, head reused as attnb
    short* Kb    = (short*)(ws + 88092672);     // 4 MiB
    short* Vtb   = (short*)(ws + 92286976);     // 4 MiB
    short* Qb    = xb;
    short* attnb = Yb;

    f32_to_bf16_k<<<4096, 256, 0, stream>>>(x, xb, 1048576);
    transpose_f32_bf16_k<<<dim3(32, 32, 1), 256, 0, stream>>>(Wq, 0, 2048, wqkvT, 0, 2048);
    transpose_f32_bf16_k<<<dim3(8, 32, 1), 256, 0, stream>>>(Wk, 0, 512, wqkvT + (size_t)2048 * 2048, 0, 2048);
    transpose_f32_bf16_k<<<dim3(8, 32, 1), 256, 0, stream>>>(Wv, 0, 512, wqkvT + (size_t)2560 * 2048, 0, 2048);
    transpose_f32_bf16_k<<<dim3(32, 32, 1), 256, 0, stream>>>(Wo, 0, 2048, woT, 0, 2048);
    concat_bias_k<<<12, 256, 0, stream>>>(bq, bk, bv, bqkv);
    gemm256_k<0, true, 3><<<dim3(16, 16), 512, 0, stream>>>(xb, wqkvT, bqkv, Yb, 4096, 3072, 2048);
    qkv_post_k<<<4096, 256, 0, stream>>>(Yb, qn, kn, sp, Qb, Kb);
    transpose_bf16_k<<<dim3(8, 32, 2), 256, 0, stream>>>(
        Yb + 2560, (size_t)2048 * 3072, 3072, Vtb, (size_t)512 * 2048, 2048);
    attn_fwd_k<<<dim3(8, 64), 512, 0, stream>>>(Qb, Kb, Vtb, gl, attnb);
    gemm256_k<1, false, 2><<<dim3(16, 16), 512, 0, stream>>>(attnb, woT, bo, out, 4096, 2048, 2048);
}

// Round 21
// 211.913 us; speedup vs baseline: 1.5060x; 1.0245x over previous
//
#include <hip/hip_runtime.h>
#include <hip/hip_bf16.h>
#include <stdint.h>

#define DEV __device__ __forceinline__

typedef short     s16x8  __attribute__((ext_vector_type(8)));
typedef __bf16    bf16v8 __attribute__((ext_vector_type(8)));
typedef float     f32x4  __attribute__((ext_vector_type(4)));
typedef float     f32x16 __attribute__((ext_vector_type(16)));
typedef unsigned int u32x2 __attribute__((ext_vector_type(2)));

// ---------- helpers ----------
DEV unsigned short f2bf(float x) {
    uint32_t u = __float_as_uint(x);
    uint32_t r = (u + 0x7FFFu + ((u >> 16) & 1u)) >> 16;
    return (unsigned short)r;
}
DEV float bf2f(uint32_t u) { return __uint_as_float(u << 16); }

DEV void gload_lds16(const void* g, void* l) {
    __builtin_amdgcn_global_load_lds((const __attribute__((address_space(1))) void*)g,
                                     (__attribute__((address_space(3))) void*)l,
                                     16, 0, 0);
}

DEV f32x4 mfma16(s16x8 a, s16x8 b, f32x4 c) {
    return __builtin_amdgcn_mfma_f32_16x16x32_bf16(
        __builtin_bit_cast(bf16v8, a), __builtin_bit_cast(bf16v8, b), c, 0, 0, 0);
}
DEV f32x16 mfma32(s16x8 a, s16x8 b, f32x16 c) {
    return __builtin_amdgcn_mfma_f32_32x32x16_bf16(
        __builtin_bit_cast(bf16v8, a), __builtin_bit_cast(bf16v8, b), c, 0, 0, 0);
}

DEV uint32_t cvtpk_bf16(float lo, float hi) {
    uint32_t r;
    asm volatile("v_cvt_pk_bf16_f32 %0, %1, %2" : "=v"(r) : "v"(lo), "v"(hi));
    return r;
}

DEV u32x2 pl32swap(uint32_t a, uint32_t b) {
    return __builtin_amdgcn_permlane32_swap(a, b, false, false);
}
DEV float cross_max(float x) {
    u32x2 r = pl32swap(__float_as_uint(x), __float_as_uint(x));
    return fmaxf(__uint_as_float(r[0]), __uint_as_float(r[1]));
}
DEV float cross_sum(float x) {
    u32x2 r = pl32swap(__float_as_uint(x), __float_as_uint(x));
    return __uint_as_float(r[0]) + __uint_as_float(r[1]);
}

DEV void barx() {
    asm volatile("" ::: "memory");
    __builtin_amdgcn_s_barrier();
    __builtin_amdgcn_sched_barrier(0);
    asm volatile("" ::: "memory");
}

// ---------- elementwise f32 -> bf16 ----------
__global__ void f32_to_bf16_k(const float* __restrict__ in, short* __restrict__ out, int n8) {
    int i = blockIdx.x * blockDim.x + threadIdx.x;
    if (i >= n8) return;
    const float4 a = *(const float4*)(in + (size_t)i * 8);
    const float4 b = *(const float4*)(in + (size_t)i * 8 + 4);
    uint4 w;
    w.x = (uint32_t)f2bf(a.x) | ((uint32_t)f2bf(a.y) << 16);
    w.y = (uint32_t)f2bf(a.z) | ((uint32_t)f2bf(a.w) << 16);
    w.z = (uint32_t)f2bf(b.x) | ((uint32_t)f2bf(b.y) << 16);
    w.w = (uint32_t)f2bf(b.z) | ((uint32_t)f2bf(b.w) << 16);
    *(uint4*)(out + (size_t)i * 8) = w;
}

// ---------- tiled transpose f32 (R x C) -> bf16 (C x R) ----------
__global__ __launch_bounds__(256) void transpose_f32_bf16_k(
    const float* __restrict__ in, size_t in_batch, int ld_in,
    short* __restrict__ out, size_t out_batch, int ld_out) {
    __shared__ float tile[64][65];
    const float* ip = in + (size_t)blockIdx.z * in_batch;
    short* op = out + (size_t)blockIdx.z * out_batch;
    const int c0 = blockIdx.x * 64, r0 = blockIdx.y * 64;
    const int t = threadIdx.x;
    const int cc4 = (t & 15) * 4;
    const int rr  = t >> 4;
#pragma unroll
    for (int p = 0; p < 4; ++p) {
        int r = rr + p * 16;
        float4 v = *(const float4*)(ip + (size_t)(r0 + r) * ld_in + c0 + cc4);
        tile[r][cc4 + 0] = v.x; tile[r][cc4 + 1] = v.y;
        tile[r][cc4 + 2] = v.z; tile[r][cc4 + 3] = v.w;
    }
    __syncthreads();
#pragma unroll
    for (int p = 0; p < 4; ++p) {
        int oc  = (t >> 4) + p * 16;
        int rr4 = (t & 15) * 4;
        ushort4 w;
        w.x = f2bf(tile[rr4 + 0][oc]);
        w.y = f2bf(tile[rr4 + 1][oc]);
        w.z = f2bf(tile[rr4 + 2][oc]);
        w.w = f2bf(tile[rr4 + 3][oc]);
        *(ushort4*)(op + (size_t)(c0 + oc) * ld_out + r0 + rr4) = w;
    }
}

// ---------- tiled transpose bf16 (R x C) -> bf16 (C x R) ----------
__global__ __launch_bounds__(256) void transpose_bf16_k(
    const short* __restrict__ in, size_t in_batch, int ld_in,
    short* __restrict__ out, size_t out_batch, int ld_out) {
    __shared__ short tile[64][72];
    const short* ip = in + (size_t)blockIdx.z * in_batch;
    short* op = out + (size_t)blockIdx.z * out_batch;
    const int c0 = blockIdx.x * 64, r0 = blockIdx.y * 64;
    const int t = threadIdx.x;
    const int cc = (t & 7) * 8;
    const int rr = t >> 3;
#pragma unroll
    for (int p = 0; p < 2; ++p) {
        int r = rr + p * 32;
        s16x8 v = *(const s16x8*)(ip + (size_t)(r0 + r) * ld_in + c0 + cc);
        *(s16x8*)&tile[r][cc] = v;
    }
    __syncthreads();
    const int oc = t >> 2;
    const int rb = (t & 3) * 16;
    s16x8 w0, w1;
#pragma unroll
    for (int j = 0; j < 8; ++j) w0[j] = tile[rb + j][oc];
#pragma unroll
    for (int j = 0; j < 8; ++j) w1[j] = tile[rb + 8 + j][oc];
    *(s16x8*)(op + (size_t)(c0 + oc) * ld_out + r0 + rb) = w0;
    *(s16x8*)(op + (size_t)(c0 + oc) * ld_out + r0 + rb + 8) = w1;
}

// ---------- bias concat ----------
__global__ void concat_bias_k(const float* __restrict__ bq, const float* __restrict__ bk,
                              const float* __restrict__ bv, float* __restrict__ o) {
    int i = blockIdx.x * 256 + threadIdx.x;
    if (i < 2048)       o[i] = bq[i];
    else if (i < 2560)  o[i] = bk[i - 2048];
    else if (i < 3072)  o[i] = bv[i - 2560];
}

// ---------- GEMM v5 (epoch-proven r20): 2-phase counted-vmcnt ----------
template<int TAG, bool OUTBF, int NF>
__global__ __launch_bounds__(512, 2) void gemm256_k(
    const short* __restrict__ A, const short* __restrict__ Bt,
    const float* __restrict__ bias, void* __restrict__ Cv,
    int M, int N, int K) {
    __shared__ short As[2][16384];
    __shared__ short Bs[2][NF * 4096];
    const int tid = threadIdx.x;
    const int gx = gridDim.x;
    const int nwg = gx * gridDim.y;
    const int flat = blockIdx.y * gx + blockIdx.x;
    const int cpx = nwg >> 3;
    const int swz = (flat & 7) * cpx + (flat >> 3);
    const int m0 = (swz / gx) * 256, n0 = (swz % gx) * (NF * 64);
    const int lane = tid & 63, wid = tid >> 6;
    const int wm = wid >> 2, wn = wid & 3;
    const int lr = lane & 15, lg = lane >> 4;

    const int srow = tid >> 3;
    const int schunk = ((tid & 7) ^ (srow & 7)) << 3;
    const short* Ag = A  + (size_t)(m0 + srow) * K + schunk;
    const short* Bg = Bt + (size_t)(n0 + srow) * K + schunk;
    const int lwb = (tid & ~63) * 8;

    f32x4 acc[8][NF];
#pragma unroll
    for (int fr = 0; fr < 8; ++fr)
#pragma unroll
        for (int fc = 0; fc < NF; ++fc)
#pragma unroll
            for (int r = 0; r < 4; ++r) acc[fr][fc][r] = 0.f;

    const int nk = K >> 6;

#define SA(u, kt, dd) gload_lds16(Ag + (size_t)(u) * 64 * K + (kt) * 64, &As[dd][(u) * 4096 + lwb])
#define SB(u, kt, dd) gload_lds16(Bg + (size_t)(u) * 64 * K + (kt) * 64, &Bs[dd][(u) * 4096 + lwb])

    SA(0, 0, 0); SA(1, 0, 0); SA(2, 0, 0); SA(3, 0, 0);
#pragma unroll
    for (int u = 0; u < NF; ++u) SB(u, 0, 0);
    asm volatile("s_waitcnt vmcnt(0)" ::: "memory");
    barx();

    for (int t = 0; t < nk; ++t) {
        const int d = t & 1, e = d ^ 1;
        const bool more = (t + 1 < nk);
        {
            s16x8 af[2][4], bf[2][NF];
#pragma unroll
            for (int ks = 0; ks < 2; ++ks) {
                const int csw = ((ks * 4 + lg) ^ (lr & 7)) * 8;
#pragma unroll
                for (int i = 0; i < 4; ++i)
                    af[ks][i] = *(const s16x8*)&As[d][(wm * 128 + i * 16 + lr) * 64 + csw];
#pragma unroll
                for (int j = 0; j < NF; ++j)
                    bf[ks][j] = *(const s16x8*)&Bs[d][(wn * (NF * 16) + j * 16 + lr) * 64 + csw];
            }
            if (more) {
                SA(0, t + 1, e); SA(2, t + 1, e);
#pragma unroll
                for (int u = 0; u < NF; ++u) SB(u, t + 1, e);
            }
            __builtin_amdgcn_s_setprio(1);
#pragma unroll
            for (int ks = 0; ks < 2; ++ks)
#pragma unroll
                for (int i = 0; i < 4; ++i)
#pragma unroll
                    for (int j = 0; j < NF; ++j)
                        acc[i][j] = mfma16(af[ks][i], bf[ks][j], acc[i][j]);
            __builtin_amdgcn_s_setprio(0);
            if (more) { asm volatile("s_waitcnt vmcnt(%0)" :: "i"(NF + 2) : "memory"); }
            else      { asm volatile("s_waitcnt vmcnt(0)" ::: "memory"); }
            barx();
        }
        {
            s16x8 af[2][4], bf[2][NF];
#pragma unroll
            for (int ks = 0; ks < 2; ++ks) {
                const int csw = ((ks * 4 + lg) ^ (lr & 7)) * 8;
#pragma unroll
                for (int i = 0; i < 4; ++i)
                    af[ks][i] = *(const s16x8*)&As[d][(wm * 128 + 64 + i * 16 + lr) * 64 + csw];
#pragma unroll
                for (int j = 0; j < NF; ++j)
                    bf[ks][j] = *(const s16x8*)&Bs[d][(wn * (NF * 16) + j * 16 + lr) * 64 + csw];
            }
            if (more) { SA(1, t + 1, e); SA(3, t + 1, e); }
            __builtin_amdgcn_s_setprio(1);
#pragma unroll
            for (int ks = 0; ks < 2; ++ks)
#pragma unroll
                for (int i = 0; i < 4; ++i)
#pragma unroll
                    for (int j = 0; j < NF; ++j)
                        acc[4 + i][j] = mfma16(af[ks][i], bf[ks][j], acc[4 + i][j]);
            __builtin_amdgcn_s_setprio(0);
            if (more) {
                asm volatile("s_waitcnt vmcnt(2)" ::: "memory");
                barx();
            }
        }
    }
#undef SA
#undef SB

#pragma unroll
    for (int fr = 0; fr < 8; ++fr) {
        const int row = m0 + wm * 128 + fr * 16 + lg * 4;
#pragma unroll
        for (int fc = 0; fc < NF; ++fc) {
            const int col = n0 + wn * (NF * 16) + fc * 16 + lr;
            const float bbv = bias[col];
            if constexpr (OUTBF) {
                short* Cs = (short*)Cv;
#pragma unroll
                for (int r = 0; r < 4; ++r)
                    Cs[(size_t)(row + r) * N + col] = (short)f2bf(acc[fr][fc][r] + bbv);
            } else {
                float* Cf = (float*)Cv;
#pragma unroll
                for (int r = 0; r < 4; ++r)
                    Cf[(size_t)(row + r) * N + col] = acc[fr][fc][r] + bbv;
            }
        }
    }
}

// ---------- rmsnorm + rope + head layout for Q,K (bf16 Y input) ----------
// Q pre-scaled by CS = log2(e)/sqrt(128).
__global__ __launch_bounds__(256) void qkv_post_k(
    const short* __restrict__ Y, const float* __restrict__ qn_w,
    const float* __restrict__ kn_w, const int* __restrict__ start_pos,
    short* __restrict__ Qb, short* __restrict__ Kb) {
    const int m = blockIdx.x;
    const int b = m >> 11, s = m & 2047;
    const short* y = Y + (size_t)m * 3072;
    const int tid = threadIdx.x;
    const float CS = 0.12751745f;

    s16x8 qv = *(const s16x8*)(y + tid * 8);
    float qn[8];
#pragma unroll
    for (int j = 0; j < 8; ++j) qn[j] = bf2f((uint32_t)(unsigned short)qv[j]);
    const uint32_t kvu = *(const uint32_t*)(y + 2048 + tid * 2);
    float k1 = bf2f(kvu & 0xffffu), k2 = bf2f(kvu >> 16);

    float ssq = qn[0]*qn[0] + qn[1]*qn[1] + qn[2]*qn[2] + qn[3]*qn[3]
              + qn[4]*qn[4] + qn[5]*qn[5] + qn[6]*qn[6] + qn[7]*qn[7];
    float ssk = k1 * k1 + k2 * k2;
#pragma unroll
    for (int off = 1; off < 64; off <<= 1) {
        ssq += __shfl_xor(ssq, off);
        ssk += __shfl_xor(ssk, off);
    }
    __shared__ float red[8];
    if ((tid & 63) == 0) { red[tid >> 6] = ssq; red[4 + (tid >> 6)] = ssk; }
    __syncthreads();
    const float tq = red[0] + red[1] + red[2] + red[3];
    const float tk = red[4] + red[5] + red[6] + red[7];
    const float rq = rsqrtf(tq * (1.f / 2048.f) + 1.1920929e-07f) * CS;
    const float rk = rsqrtf(tk * (1.f / 512.f) + 1.1920929e-07f);
    const int pos = start_pos[0] + s;

#pragma unroll
    for (int j = 0; j < 8; ++j) qn[j] *= rq * qn_w[tid * 8 + j];
    const int hq = tid >> 4;
    const int din = (tid * 8) & 127;
    unsigned short ob[8];
#pragma unroll
    for (int j = 0; j < 4; ++j) {
        int tt = (din >> 1) + j;
        float inv = __builtin_exp2f(-0.20762050f * (float)tt);
        float ang = (float)pos * inv;
        float sn, cn;
        __sincosf(ang, &sn, &cn);
        float x1 = qn[2 * j], x2 = qn[2 * j + 1];
        ob[2 * j]     = f2bf(x1 * cn - x2 * sn);
        ob[2 * j + 1] = f2bf(x1 * sn + x2 * cn);
    }
    short* qdst = Qb + (((size_t)(b * 16 + hq) * 2048 + s) * 128 + din);
    uint4 w;
    w.x = (uint32_t)ob[0] | ((uint32_t)ob[1] << 16);
    w.y = (uint32_t)ob[2] | ((uint32_t)ob[3] << 16);
    w.z = (uint32_t)ob[4] | ((uint32_t)ob[5] << 16);
    w.w = (uint32_t)ob[6] | ((uint32_t)ob[7] << 16);
    *(uint4*)qdst = w;

    const int colk = tid * 2;
    const int hk = colk >> 7, dk = colk & 127;
    float kk1 = k1 * rk * kn_w[colk], kk2 = k2 * rk * kn_w[colk + 1];
    {
        int tt = dk >> 1;
        float inv = __builtin_exp2f(-0.20762050f * (float)tt);
        float ang = (float)pos * inv;
        float sn, cn;
        __sincosf(ang, &sn, &cn);
        float r1 = kk1 * cn - kk2 * sn, r2 = kk1 * sn + kk2 * cn;
        short* kdst = Kb + (((size_t)(b * 4 + hk) * 2048 + s) * 128 + dk);
        *(uint32_t*)kdst = (uint32_t)f2bf(r1) | ((uint32_t)f2bf(r2) << 16);
    }
}

// ---------- flash attention v10: v9b + split-wait (K ready early, V-load
// latency hidden under QK^T+softmax via counted vmcnt + raw barrier — the
// epoch-proven GEMM idiom). LDS shrunk to 64KB: merge buffer overlaid into
// dead KV (O as bf16 in KV[0], m/l at KV[1]).
__global__ __launch_bounds__(512, 1) void attn_fwd_k(
    const short* __restrict__ Qb, const short* __restrict__ Kb,
    const short* __restrict__ Vtb, const float* __restrict__ gate_logits,
    short* __restrict__ attnb) {
    const int S = 2048;
    __shared__ short KV[2][16384];     // per-group: K 8192 | V 8192 shorts
    const int tid = threadIdx.x, lane = tid & 63;
    const int wid = tid >> 6;
    const int g = wid >> 2;
    const int hw = wid & 3;
    const int y = blockIdx.y;
    const int qt = (y < 32) ? (63 - y) : (y - 32);
    const int bhk = blockIdx.x;
    const int b = bhk >> 2, hk = bhk & 3;
    const int h = hk * 4 + hw;
    const int n = (qt + 2) >> 1;
    const int nh = (n + 1) >> 1, nl = n - nh;
    const int q0 = qt * 32;
    const int ql = lane & 31, hi = lane >> 5;
    const int qg = q0 + ql;
    const float THR = 11.5416f;        // 8 * log2(e)
    const float gl = gate_logits[h];
    const float gate = 1.f / (1.f + __expf(-gl));

    s16x8 qf[8];
#pragma unroll
    for (int kc = 0; kc < 8; ++kc)
        qf[kc] = *(const s16x8*)(Qb + (((size_t)(b * 16 + h) * S + qg) * 128 + hi * 8) + kc * 16);

    f32x16 ov[4];
#pragma unroll
    for (int dc = 0; dc < 4; ++dc)
#pragma unroll
        for (int r = 0; r < 16; ++r) ov[dc][r] = 0.f;
    float mrun = -3.0e38f, lrun = 0.f;

    const int g256 = tid & 255;
    const short* kg[4]; const short* vg[4]; int lb[4];
#pragma unroll
    for (int i = 0; i < 4; ++i) {
        int oo = (i * 256 + g256) * 8;
        lb[i] = (i * 256 + (g256 & ~63)) * 8;
        {
            int row = oo >> 7, col = oo & 127, ch = col >> 3;
            kg[i] = Kb + ((size_t)bhk * S + row) * 128 + ((ch ^ (row & 7)) << 3);
        }
        {
            int row = oo >> 6, col = oo & 63, ch = col >> 3;
            vg[i] = Vtb + ((size_t)bhk * 128 + row) * S + ((ch ^ (row & 7)) << 3);
        }
    }

// issues K loads (4/thread) FIRST, then V loads (4/thread): vmcnt(4) => K landed
#define STAGE_TILE(jj) do {                                                      \
        const int base_ = (jj) * 64;                                             \
        _Pragma("unroll")                                                        \
        for (int i_ = 0; i_ < 4; ++i_)                                           \
            gload_lds16(kg[i_] + (size_t)base_ * 128, &KV[g][lb[i_]]);           \
        _Pragma("unroll")                                                        \
        for (int i_ = 0; i_ < 4; ++i_)                                           \
            gload_lds16(vg[i_] + base_, &KV[g][8192 + lb[i_]]);                  \
    } while (0)

    for (int it = 0; it < nh; ++it) {
        const int j = (g == 0) ? it : (nh + it);
        const bool active = (g == 0) || (it < nl);
        if (it > 0) __syncthreads();              // prior compute done before overwrite
        if (active) STAGE_TILE(j);
        asm volatile("s_waitcnt vmcnt(4)" ::: "memory");   // own K loads retired
        barx();                                            // all K writes visible
        const int j0 = j * 64;
        const bool have1 = (j0 + 32 <= q0 + 31);
        union { uint32_t u[4]; s16x8 v; } f00, f01, f10, f11;
        if (active) {
            const short* Ks = &KV[g][0];
            const bool fsub0 = (j0 + 31 <= q0);
            const bool fsub1 = (j0 + 63 <= q0);
            f32x16 s0, s1;
#pragma unroll
            for (int r = 0; r < 16; ++r) { s0[r] = 0.f; s1[r] = 0.f; }
            __builtin_amdgcn_s_setprio(1);
#pragma unroll
            for (int kc = 0; kc < 8; ++kc) {
                const int c = kc * 2 + hi;
                s16x8 kf0 = *(const s16x8*)&Ks[ql * 128 + ((c ^ (ql & 7)) << 3)];
                s0 = mfma32(kf0, qf[kc], s0);
            }
            if (have1) {
#pragma unroll
                for (int kc = 0; kc < 8; ++kc) {
                    const int c = kc * 2 + hi;
                    const int kr = 32 + ql;
                    s16x8 kf1 = *(const s16x8*)&Ks[kr * 128 + ((c ^ (kr & 7)) << 3)];
                    s1 = mfma32(kf1, qf[kc], s1);
                }
            }
            __builtin_amdgcn_s_setprio(0);
            float p0[16], p1[16];
            if (fsub0) {
#pragma unroll
                for (int r = 0; r < 16; ++r) p0[r] = s0[r];
            } else {
#pragma unroll
                for (int r = 0; r < 16; ++r) {
                    int kvg = j0 + ((r & 3) + 8 * (r >> 2) + 4 * hi);
                    p0[r] = (kvg <= qg) ? s0[r] : -3.0e38f;
                }
            }
            if (have1) {
                if (fsub1) {
#pragma unroll
                    for (int r = 0; r < 16; ++r) p1[r] = s1[r];
                } else {
#pragma unroll
                    for (int r = 0; r < 16; ++r) {
                        int kvg = j0 + 32 + ((r & 3) + 8 * (r >> 2) + 4 * hi);
                        p1[r] = (kvg <= qg) ? s1[r] : -3.0e38f;
                    }
                }
            }
            float a0 = fmaxf(p0[0], p0[1]),  a1 = fmaxf(p0[2], p0[3]);
            float a2 = fmaxf(p0[4], p0[5]),  a3 = fmaxf(p0[6], p0[7]);
            float a4 = fmaxf(p0[8], p0[9]),  a5 = fmaxf(p0[10], p0[11]);
            float a6 = fmaxf(p0[12], p0[13]), a7 = fmaxf(p0[14], p0[15]);
            float pmax = fmaxf(fmaxf(fmaxf(a0, a1), fmaxf(a2, a3)),
                               fmaxf(fmaxf(a4, a5), fmaxf(a6, a7)));
            if (have1) {
                float b0 = fmaxf(p1[0], p1[1]),  b1 = fmaxf(p1[2], p1[3]);
                float b2 = fmaxf(p1[4], p1[5]),  b3 = fmaxf(p1[6], p1[7]);
                float b4 = fmaxf(p1[8], p1[9]),  b5 = fmaxf(p1[10], p1[11]);
                float b6 = fmaxf(p1[12], p1[13]), b7 = fmaxf(p1[14], p1[15]);
                pmax = fmaxf(pmax, fmaxf(fmaxf(fmaxf(b0, b1), fmaxf(b2, b3)),
                                         fmaxf(fmaxf(b4, b5), fmaxf(b6, b7))));
            }
            pmax = cross_max(pmax);
            if (__any(pmax - mrun > THR)) {
                float mnew = fmaxf(mrun, pmax);
                float alpha = __builtin_exp2f(mrun - mnew);
                lrun *= alpha;
#pragma unroll
                for (int r = 0; r < 16; ++r) {
                    int cr = (r & 3) + 8 * (r >> 2) + 4 * hi;
                    float ar = __uint_as_float(
                        (uint32_t)__builtin_amdgcn_ds_bpermute(cr << 2, (int)__float_as_uint(alpha)));
                    ov[0][r] *= ar; ov[1][r] *= ar; ov[2][r] *= ar; ov[3][r] *= ar;
                }
                mrun = mnew;
            }
#pragma unroll
            for (int r = 0; r < 16; ++r) p0[r] = __builtin_exp2f(p0[r] - mrun);
            float ps;
            {
                float t0 = (p0[0] + p0[1]) + (p0[2] + p0[3]);
                float t1 = (p0[4] + p0[5]) + (p0[6] + p0[7]);
                float t2 = (p0[8] + p0[9]) + (p0[10] + p0[11]);
                float t3 = (p0[12] + p0[13]) + (p0[14] + p0[15]);
                ps = (t0 + t1) + (t2 + t3);
            }
            if (have1) {
#pragma unroll
                for (int r = 0; r < 16; ++r) p1[r] = __builtin_exp2f(p1[r] - mrun);
                float t0 = (p1[0] + p1[1]) + (p1[2] + p1[3]);
                float t1 = (p1[4] + p1[5]) + (p1[6] + p1[7]);
                float t2 = (p1[8] + p1[9]) + (p1[10] + p1[11]);
                float t3 = (p1[12] + p1[13]) + (p1[14] + p1[15]);
                ps += (t0 + t1) + (t2 + t3);
            }
            lrun += cross_sum(ps);
            {
                uint32_t w0 = cvtpk_bf16(p0[0], p0[1]),   w1 = cvtpk_bf16(p0[2], p0[3]);
                uint32_t w2 = cvtpk_bf16(p0[4], p0[5]),   w3 = cvtpk_bf16(p0[6], p0[7]);
                uint32_t w4 = cvtpk_bf16(p0[8], p0[9]),   w5 = cvtpk_bf16(p0[10], p0[11]);
                uint32_t w6 = cvtpk_bf16(p0[12], p0[13]), w7 = cvtpk_bf16(p0[14], p0[15]);
                u32x2 r02 = pl32swap(w0, w2); f00.u[0] = r02[0]; f00.u[2] = r02[1];
                u32x2 r13 = pl32swap(w1, w3); f00.u[1] = r13[0]; f00.u[3] = r13[1];
                u32x2 r46 = pl32swap(w4, w6); f01.u[0] = r46[0]; f01.u[2] = r46[1];
                u32x2 r57 = pl32swap(w5, w7); f01.u[1] = r57[0]; f01.u[3] = r57[1];
            }
            if (have1) {
                uint32_t w0 = cvtpk_bf16(p1[0], p1[1]),   w1 = cvtpk_bf16(p1[2], p1[3]);
                uint32_t w2 = cvtpk_bf16(p1[4], p1[5]),   w3 = cvtpk_bf16(p1[6], p1[7]);
                uint32_t w4 = cvtpk_bf16(p1[8], p1[9]),   w5 = cvtpk_bf16(p1[10], p1[11]);
                uint32_t w6 = cvtpk_bf16(p1[12], p1[13]), w7 = cvtpk_bf16(p1[14], p1[15]);
                u32x2 r02 = pl32swap(w0, w2); f10.u[0] = r02[0]; f10.u[2] = r02[1];
                u32x2 r13 = pl32swap(w1, w3); f10.u[1] = r13[0]; f10.u[3] = r13[1];
                u32x2 r46 = pl32swap(w4, w6); f11.u[0] = r46[0]; f11.u[2] = r46[1];
                u32x2 r57 = pl32swap(w5, w7); f11.u[1] = r57[0]; f11.u[3] = r57[1];
            }
        }
        asm volatile("s_waitcnt vmcnt(0)" ::: "memory");   // V loads retired
        barx();                                            // all V writes visible
        if (active) {
            const short* Vs = &KV[g][8192];
            __builtin_amdgcn_s_setprio(1);
#pragma unroll
            for (int dc = 0; dc < 4; ++dc) {
                const int dd = dc * 32 + ql;
                const int sw = (dd & 7);
                s16x8 v0 = *(const s16x8*)&Vs[dd * 64 + (((hi) ^ sw) << 3)];
                ov[dc] = mfma32(f00.v, v0, ov[dc]);
                s16x8 v1 = *(const s16x8*)&Vs[dd * 64 + (((2 + hi) ^ sw) << 3)];
                ov[dc] = mfma32(f01.v, v1, ov[dc]);
                if (have1) {
                    s16x8 v2 = *(const s16x8*)&Vs[dd * 64 + (((4 + hi) ^ sw) << 3)];
                    ov[dc] = mfma32(f10.v, v2, ov[dc]);
                    s16x8 v3 = *(const s16x8*)&Vs[dd * 64 + (((6 + hi) ^ sw) << 3)];
                    ov[dc] = mfma32(f11.v, v3, ov[dc]);
                }
            }
            __builtin_amdgcn_s_setprio(0);
        }
    }

    // ---- merge: g1 partial -> g0, overlaid into dead KV ----
    __syncthreads();                               // all compute reads of KV done
    short* mbO = &KV[0][0];                        // 16384 shorts = 32KB (bf16 O)
    float* Msm2 = (float*)&KV[1][0];               // 256 floats
    float* Lsm2 = Msm2 + 256;                      // 256 floats
    if (g == 1) {
#pragma unroll
        for (int dc = 0; dc < 4; ++dc)
#pragma unroll
            for (int r = 0; r < 16; ++r)
                mbO[hw * 4096 + lane * 64 + dc * 16 + r] = (short)f2bf(ov[dc][r]);
        Msm2[hw * 64 + lane] = mrun;
        Lsm2[hw * 64 + lane] = lrun;
    }
    __syncthreads();
    if (g == 0) {
        const float m1 = Msm2[hw * 64 + lane];
        const float l1 = Lsm2[hw * 64 + lane];
        const float mm = fmaxf(mrun, m1);
        const float al0 = __builtin_exp2f(mrun - mm);
        const float al1 = __builtin_exp2f(m1 - mm);
        lrun = lrun * al0 + l1 * al1;
#pragma unroll
        for (int r = 0; r < 16; ++r) {
            int cr = (r & 3) + 8 * (r >> 2) + 4 * hi;
            float a0r = __uint_as_float(
                (uint32_t)__builtin_amdgcn_ds_bpermute(cr << 2, (int)__float_as_uint(al0)));
            float a1r = __uint_as_float(
                (uint32_t)__builtin_amdgcn_ds_bpermute(cr << 2, (int)__float_as_uint(al1)));
#pragma unroll
            for (int dc = 0; dc < 4; ++dc) {
                float o1 = bf2f((uint32_t)(unsigned short)mbO[hw * 4096 + lane * 64 + dc * 16 + r]);
                ov[dc][r] = ov[dc][r] * a0r + o1 * a1r;
            }
        }
        const float linv = gate / lrun;
#pragma unroll
        for (int r = 0; r < 16; ++r) {
            int cr = (r & 3) + 8 * (r >> 2) + 4 * hi;
            float sc = __uint_as_float(
                (uint32_t)__builtin_amdgcn_ds_bpermute(cr << 2, (int)__float_as_uint(linv)));
            int qrow = q0 + cr;
            short* orow = attnb + ((size_t)(b * S) + qrow) * 2048 + h * 128 + ql;
#pragma unroll
            for (int dc = 0; dc < 4; ++dc)
                orow[dc * 32] = (short)f2bf(ov[dc][r] * sc);
        }
    }
#undef STAGE_TILE
}

// ---------- launch ----------
extern "C" void kernel_launch(void* const* d_in, const int* in_sizes, int n_in,
                              void* d_out, int out_size, void* d_ws, size_t ws_size,
                              hipStream_t stream) {
    const float* x  = (const float*)d_in[0];
    const float* Wq = (const float*)d_in[1];
    const float* bq = (const float*)d_in[2];
    const float* Wk = (const float*)d_in[3];
    const float* bk = (const float*)d_in[4];
    const float* Wv = (const float*)d_in[5];
    const float* bv = (const float*)d_in[6];
    const float* Wo = (const float*)d_in[7];
    const float* bo = (const float*)d_in[8];
    const float* qn = (const float*)d_in[9];
    const float* kn = (const float*)d_in[10];
    const float* gl = (const float*)d_in[11];
    const int* sp   = (const int*)d_in[13];
    float* out = (float*)d_out;

    char* ws = (char*)d_ws;
    const size_t NEED = 96481280;
    if (ws_size < NEED) return;
    short* xb    = (short*)(ws + 0);            // 16 MiB, reused as Qb
    short* wqkvT = (short*)(ws + 16777216);     // 12 MiB
    short* woT   = (short*)(ws + 29360128);     // 8 MiB
    float* bqkv  = (float*)(ws + 37748736);     // 12 KiB
    short* Yb    = (short*)(ws + 37761024);     // 24 MiB bf16, head reused as attnb
    short* Kb    = (short*)(ws + 88092672);     // 4 MiB
    short* Vtb   = (short*)(ws + 92286976);     // 4 MiB
    short* Qb    = xb;
    short* attnb = Yb;

    f32_to_bf16_k<<<4096, 256, 0, stream>>>(x, xb, 1048576);
    transpose_f32_bf16_k<<<dim3(32, 32, 1), 256, 0, stream>>>(Wq, 0, 2048, wqkvT, 0, 2048);
    transpose_f32_bf16_k<<<dim3(8, 32, 1), 256, 0, stream>>>(Wk, 0, 512, wqkvT + (size_t)2048 * 2048, 0, 2048);
    transpose_f32_bf16_k<<<dim3(8, 32, 1), 256, 0, stream>>>(Wv, 0, 512, wqkvT + (size_t)2560 * 2048, 0, 2048);
    transpose_f32_bf16_k<<<dim3(32, 32, 1), 256, 0, stream>>>(Wo, 0, 2048, woT, 0, 2048);
    concat_bias_k<<<12, 256, 0, stream>>>(bq, bk, bv, bqkv);
    gemm256_k<0, true, 3><<<dim3(16, 16), 512, 0, stream>>>(xb, wqkvT, bqkv, Yb, 4096, 3072, 2048);
    qkv_post_k<<<4096, 256, 0, stream>>>(Yb, qn, kn, sp, Qb, Kb);
    transpose_bf16_k<<<dim3(8, 32, 2), 256, 0, stream>>>(
        Yb + 2560, (size_t)2048 * 3072, 3072, Vtb, (size_t)512 * 2048, 2048);
    attn_fwd_k<<<dim3(8, 64), 512, 0, stream>>>(Qb, Kb, Vtb, gl, attnb);
    gemm256_k<1, false, 2><<<dim3(16, 16), 512, 0, stream>>>(attnb, woT, bo, out, 4096, 2048, 2048);
}

// Round 22
// 208.874 us; speedup vs baseline: 1.5279x; 1.0145x over previous
//
#include <hip/hip_runtime.h>
#include <hip/hip_bf16.h>
#include <stdint.h>

#define DEV __device__ __forceinline__

typedef short     s16x8  __attribute__((ext_vector_type(8)));
typedef __bf16    bf16v8 __attribute__((ext_vector_type(8)));
typedef float     f32x4  __attribute__((ext_vector_type(4)));
typedef float     f32x16 __attribute__((ext_vector_type(16)));
typedef unsigned int u32x2 __attribute__((ext_vector_type(2)));

// ---------- helpers ----------
DEV unsigned short f2bf(float x) {
    uint32_t u = __float_as_uint(x);
    uint32_t r = (u + 0x7FFFu + ((u >> 16) & 1u)) >> 16;
    return (unsigned short)r;
}
DEV float bf2f(uint32_t u) { return __uint_as_float(u << 16); }

DEV void gload_lds16(const void* g, void* l) {
    __builtin_amdgcn_global_load_lds((const __attribute__((address_space(1))) void*)g,
                                     (__attribute__((address_space(3))) void*)l,
                                     16, 0, 0);
}

DEV f32x4 mfma16(s16x8 a, s16x8 b, f32x4 c) {
    return __builtin_amdgcn_mfma_f32_16x16x32_bf16(
        __builtin_bit_cast(bf16v8, a), __builtin_bit_cast(bf16v8, b), c, 0, 0, 0);
}
DEV f32x16 mfma32(s16x8 a, s16x8 b, f32x16 c) {
    return __builtin_amdgcn_mfma_f32_32x32x16_bf16(
        __builtin_bit_cast(bf16v8, a), __builtin_bit_cast(bf16v8, b), c, 0, 0, 0);
}

DEV uint32_t cvtpk_bf16(float lo, float hi) {
    uint32_t r;
    asm volatile("v_cvt_pk_bf16_f32 %0, %1, %2" : "=v"(r) : "v"(lo), "v"(hi));
    return r;
}

DEV u32x2 pl32swap(uint32_t a, uint32_t b) {
    return __builtin_amdgcn_permlane32_swap(a, b, false, false);
}
DEV float cross_max(float x) {
    u32x2 r = pl32swap(__float_as_uint(x), __float_as_uint(x));
    return fmaxf(__uint_as_float(r[0]), __uint_as_float(r[1]));
}
DEV float cross_sum(float x) {
    u32x2 r = pl32swap(__float_as_uint(x), __float_as_uint(x));
    return __uint_as_float(r[0]) + __uint_as_float(r[1]);
}

DEV void barx() {
    asm volatile("" ::: "memory");
    __builtin_amdgcn_s_barrier();
    __builtin_amdgcn_sched_barrier(0);
    asm volatile("" ::: "memory");
}

// ---------- elementwise f32 -> bf16 ----------
__global__ void f32_to_bf16_k(const float* __restrict__ in, short* __restrict__ out, int n8) {
    int i = blockIdx.x * blockDim.x + threadIdx.x;
    if (i >= n8) return;
    const float4 a = *(const float4*)(in + (size_t)i * 8);
    const float4 b = *(const float4*)(in + (size_t)i * 8 + 4);
    uint4 w;
    w.x = (uint32_t)f2bf(a.x) | ((uint32_t)f2bf(a.y) << 16);
    w.y = (uint32_t)f2bf(a.z) | ((uint32_t)f2bf(a.w) << 16);
    w.z = (uint32_t)f2bf(b.x) | ((uint32_t)f2bf(b.y) << 16);
    w.w = (uint32_t)f2bf(b.z) | ((uint32_t)f2bf(b.w) << 16);
    *(uint4*)(out + (size_t)i * 8) = w;
}

// ---------- tiled transpose f32 (R x C) -> bf16 (C x R) ----------
__global__ __launch_bounds__(256) void transpose_f32_bf16_k(
    const float* __restrict__ in, size_t in_batch, int ld_in,
    short* __restrict__ out, size_t out_batch, int ld_out) {
    __shared__ float tile[64][65];
    const float* ip = in + (size_t)blockIdx.z * in_batch;
    short* op = out + (size_t)blockIdx.z * out_batch;
    const int c0 = blockIdx.x * 64, r0 = blockIdx.y * 64;
    const int t = threadIdx.x;
    const int cc4 = (t & 15) * 4;
    const int rr  = t >> 4;
#pragma unroll
    for (int p = 0; p < 4; ++p) {
        int r = rr + p * 16;
        float4 v = *(const float4*)(ip + (size_t)(r0 + r) * ld_in + c0 + cc4);
        tile[r][cc4 + 0] = v.x; tile[r][cc4 + 1] = v.y;
        tile[r][cc4 + 2] = v.z; tile[r][cc4 + 3] = v.w;
    }
    __syncthreads();
#pragma unroll
    for (int p = 0; p < 4; ++p) {
        int oc  = (t >> 4) + p * 16;
        int rr4 = (t & 15) * 4;
        ushort4 w;
        w.x = f2bf(tile[rr4 + 0][oc]);
        w.y = f2bf(tile[rr4 + 1][oc]);
        w.z = f2bf(tile[rr4 + 2][oc]);
        w.w = f2bf(tile[rr4 + 3][oc]);
        *(ushort4*)(op + (size_t)(c0 + oc) * ld_out + r0 + rr4) = w;
    }
}

// ---------- tiled transpose bf16 (R x C) -> bf16 (C x R) ----------
__global__ __launch_bounds__(256) void transpose_bf16_k(
    const short* __restrict__ in, size_t in_batch, int ld_in,
    short* __restrict__ out, size_t out_batch, int ld_out) {
    __shared__ short tile[64][72];
    const short* ip = in + (size_t)blockIdx.z * in_batch;
    short* op = out + (size_t)blockIdx.z * out_batch;
    const int c0 = blockIdx.x * 64, r0 = blockIdx.y * 64;
    const int t = threadIdx.x;
    const int cc = (t & 7) * 8;
    const int rr = t >> 3;
#pragma unroll
    for (int p = 0; p < 2; ++p) {
        int r = rr + p * 32;
        s16x8 v = *(const s16x8*)(ip + (size_t)(r0 + r) * ld_in + c0 + cc);
        *(s16x8*)&tile[r][cc] = v;
    }
    __syncthreads();
    const int oc = t >> 2;
    const int rb = (t & 3) * 16;
    s16x8 w0, w1;
#pragma unroll
    for (int j = 0; j < 8; ++j) w0[j] = tile[rb + j][oc];
#pragma unroll
    for (int j = 0; j < 8; ++j) w1[j] = tile[rb + 8 + j][oc];
    *(s16x8*)(op + (size_t)(c0 + oc) * ld_out + r0 + rb) = w0;
    *(s16x8*)(op + (size_t)(c0 + oc) * ld_out + r0 + rb + 8) = w1;
}

// ---------- bias concat ----------
__global__ void concat_bias_k(const float* __restrict__ bq, const float* __restrict__ bk,
                              const float* __restrict__ bv, float* __restrict__ o) {
    int i = blockIdx.x * 256 + threadIdx.x;
    if (i < 2048)       o[i] = bq[i];
    else if (i < 2560)  o[i] = bk[i - 2048];
    else if (i < 3072)  o[i] = bv[i - 2560];
}

// ---------- GEMM v5 (epoch-proven r20/r21): 2-phase counted-vmcnt ----------
template<int TAG, bool OUTBF, int NF>
__global__ __launch_bounds__(512, 2) void gemm256_k(
    const short* __restrict__ A, const short* __restrict__ Bt,
    const float* __restrict__ bias, void* __restrict__ Cv,
    int M, int N, int K) {
    __shared__ short As[2][16384];
    __shared__ short Bs[2][NF * 4096];
    const int tid = threadIdx.x;
    const int gx = gridDim.x;
    const int nwg = gx * gridDim.y;
    const int flat = blockIdx.y * gx + blockIdx.x;
    const int cpx = nwg >> 3;
    const int swz = (flat & 7) * cpx + (flat >> 3);
    const int m0 = (swz / gx) * 256, n0 = (swz % gx) * (NF * 64);
    const int lane = tid & 63, wid = tid >> 6;
    const int wm = wid >> 2, wn = wid & 3;
    const int lr = lane & 15, lg = lane >> 4;

    const int srow = tid >> 3;
    const int schunk = ((tid & 7) ^ (srow & 7)) << 3;
    const short* Ag = A  + (size_t)(m0 + srow) * K + schunk;
    const short* Bg = Bt + (size_t)(n0 + srow) * K + schunk;
    const int lwb = (tid & ~63) * 8;

    f32x4 acc[8][NF];
#pragma unroll
    for (int fr = 0; fr < 8; ++fr)
#pragma unroll
        for (int fc = 0; fc < NF; ++fc)
#pragma unroll
            for (int r = 0; r < 4; ++r) acc[fr][fc][r] = 0.f;

    const int nk = K >> 6;

#define SA(u, kt, dd) gload_lds16(Ag + (size_t)(u) * 64 * K + (kt) * 64, &As[dd][(u) * 4096 + lwb])
#define SB(u, kt, dd) gload_lds16(Bg + (size_t)(u) * 64 * K + (kt) * 64, &Bs[dd][(u) * 4096 + lwb])

    SA(0, 0, 0); SA(1, 0, 0); SA(2, 0, 0); SA(3, 0, 0);
#pragma unroll
    for (int u = 0; u < NF; ++u) SB(u, 0, 0);
    asm volatile("s_waitcnt vmcnt(0)" ::: "memory");
    barx();

    for (int t = 0; t < nk; ++t) {
        const int d = t & 1, e = d ^ 1;
        const bool more = (t + 1 < nk);
        {
            s16x8 af[2][4], bf[2][NF];
#pragma unroll
            for (int ks = 0; ks < 2; ++ks) {
                const int csw = ((ks * 4 + lg) ^ (lr & 7)) * 8;
#pragma unroll
                for (int i = 0; i < 4; ++i)
                    af[ks][i] = *(const s16x8*)&As[d][(wm * 128 + i * 16 + lr) * 64 + csw];
#pragma unroll
                for (int j = 0; j < NF; ++j)
                    bf[ks][j] = *(const s16x8*)&Bs[d][(wn * (NF * 16) + j * 16 + lr) * 64 + csw];
            }
            if (more) {
                SA(0, t + 1, e); SA(2, t + 1, e);
#pragma unroll
                for (int u = 0; u < NF; ++u) SB(u, t + 1, e);
            }
            __builtin_amdgcn_s_setprio(1);
#pragma unroll
            for (int ks = 0; ks < 2; ++ks)
#pragma unroll
                for (int i = 0; i < 4; ++i)
#pragma unroll
                    for (int j = 0; j < NF; ++j)
                        acc[i][j] = mfma16(af[ks][i], bf[ks][j], acc[i][j]);
            __builtin_amdgcn_s_setprio(0);
            if (more) { asm volatile("s_waitcnt vmcnt(%0)" :: "i"(NF + 2) : "memory"); }
            else      { asm volatile("s_waitcnt vmcnt(0)" ::: "memory"); }
            barx();
        }
        {
            s16x8 af[2][4], bf[2][NF];
#pragma unroll
            for (int ks = 0; ks < 2; ++ks) {
                const int csw = ((ks * 4 + lg) ^ (lr & 7)) * 8;
#pragma unroll
                for (int i = 0; i < 4; ++i)
                    af[ks][i] = *(const s16x8*)&As[d][(wm * 128 + 64 + i * 16 + lr) * 64 + csw];
#pragma unroll
                for (int j = 0; j < NF; ++j)
                    bf[ks][j] = *(const s16x8*)&Bs[d][(wn * (NF * 16) + j * 16 + lr) * 64 + csw];
            }
            if (more) { SA(1, t + 1, e); SA(3, t + 1, e); }
            __builtin_amdgcn_s_setprio(1);
#pragma unroll
            for (int ks = 0; ks < 2; ++ks)
#pragma unroll
                for (int i = 0; i < 4; ++i)
#pragma unroll
                    for (int j = 0; j < NF; ++j)
                        acc[4 + i][j] = mfma16(af[ks][i], bf[ks][j], acc[4 + i][j]);
            __builtin_amdgcn_s_setprio(0);
            if (more) {
                asm volatile("s_waitcnt vmcnt(2)" ::: "memory");
                barx();
            }
        }
    }
#undef SA
#undef SB

#pragma unroll
    for (int fr = 0; fr < 8; ++fr) {
        const int row = m0 + wm * 128 + fr * 16 + lg * 4;
#pragma unroll
        for (int fc = 0; fc < NF; ++fc) {
            const int col = n0 + wn * (NF * 16) + fc * 16 + lr;
            const float bbv = bias[col];
            if constexpr (OUTBF) {
                short* Cs = (short*)Cv;
#pragma unroll
                for (int r = 0; r < 4; ++r)
                    Cs[(size_t)(row + r) * N + col] = (short)f2bf(acc[fr][fc][r] + bbv);
            } else {
                float* Cf = (float*)Cv;
#pragma unroll
                for (int r = 0; r < 4; ++r)
                    Cf[(size_t)(row + r) * N + col] = acc[fr][fc][r] + bbv;
            }
        }
    }
}

// ---------- rmsnorm + rope + head layout for Q,K (bf16 Y input) ----------
// Q pre-scaled by CS = log2(e)/sqrt(128).
__global__ __launch_bounds__(256) void qkv_post_k(
    const short* __restrict__ Y, const float* __restrict__ qn_w,
    const float* __restrict__ kn_w, const int* __restrict__ start_pos,
    short* __restrict__ Qb, short* __restrict__ Kb) {
    const int m = blockIdx.x;
    const int b = m >> 11, s = m & 2047;
    const short* y = Y + (size_t)m * 3072;
    const int tid = threadIdx.x;
    const float CS = 0.12751745f;

    s16x8 qv = *(const s16x8*)(y + tid * 8);
    float qn[8];
#pragma unroll
    for (int j = 0; j < 8; ++j) qn[j] = bf2f((uint32_t)(unsigned short)qv[j]);
    const uint32_t kvu = *(const uint32_t*)(y + 2048 + tid * 2);
    float k1 = bf2f(kvu & 0xffffu), k2 = bf2f(kvu >> 16);

    float ssq = qn[0]*qn[0] + qn[1]*qn[1] + qn[2]*qn[2] + qn[3]*qn[3]
              + qn[4]*qn[4] + qn[5]*qn[5] + qn[6]*qn[6] + qn[7]*qn[7];
    float ssk = k1 * k1 + k2 * k2;
#pragma unroll
    for (int off = 1; off < 64; off <<= 1) {
        ssq += __shfl_xor(ssq, off);
        ssk += __shfl_xor(ssk, off);
    }
    __shared__ float red[8];
    if ((tid & 63) == 0) { red[tid >> 6] = ssq; red[4 + (tid >> 6)] = ssk; }
    __syncthreads();
    const float tq = red[0] + red[1] + red[2] + red[3];
    const float tk = red[4] + red[5] + red[6] + red[7];
    const float rq = rsqrtf(tq * (1.f / 2048.f) + 1.1920929e-07f) * CS;
    const float rk = rsqrtf(tk * (1.f / 512.f) + 1.1920929e-07f);
    const int pos = start_pos[0] + s;

#pragma unroll
    for (int j = 0; j < 8; ++j) qn[j] *= rq * qn_w[tid * 8 + j];
    const int hq = tid >> 4;
    const int din = (tid * 8) & 127;
    unsigned short ob[8];
#pragma unroll
    for (int j = 0; j < 4; ++j) {
        int tt = (din >> 1) + j;
        float inv = __builtin_exp2f(-0.20762050f * (float)tt);
        float ang = (float)pos * inv;
        float sn, cn;
        __sincosf(ang, &sn, &cn);
        float x1 = qn[2 * j], x2 = qn[2 * j + 1];
        ob[2 * j]     = f2bf(x1 * cn - x2 * sn);
        ob[2 * j + 1] = f2bf(x1 * sn + x2 * cn);
    }
    short* qdst = Qb + (((size_t)(b * 16 + hq) * 2048 + s) * 128 + din);
    uint4 w;
    w.x = (uint32_t)ob[0] | ((uint32_t)ob[1] << 16);
    w.y = (uint32_t)ob[2] | ((uint32_t)ob[3] << 16);
    w.z = (uint32_t)ob[4] | ((uint32_t)ob[5] << 16);
    w.w = (uint32_t)ob[6] | ((uint32_t)ob[7] << 16);
    *(uint4*)qdst = w;

    const int colk = tid * 2;
    const int hk = colk >> 7, dk = colk & 127;
    float kk1 = k1 * rk * kn_w[colk], kk2 = k2 * rk * kn_w[colk + 1];
    {
        int tt = dk >> 1;
        float inv = __builtin_exp2f(-0.20762050f * (float)tt);
        float ang = (float)pos * inv;
        float sn, cn;
        __sincosf(ang, &sn, &cn);
        float r1 = kk1 * cn - kk2 * sn, r2 = kk1 * sn + kk2 * cn;
        short* kdst = Kb + (((size_t)(b * 4 + hk) * 2048 + s) * 128 + dk);
        *(uint32_t*)kdst = (uint32_t)f2bf(r1) | ((uint32_t)f2bf(r2) << 16);
    }
}

// ---------- flash attention v11: v10 + K-prefetch-one-iter-ahead ----------
// Same single 64KB buffer and counted-vmcnt/barx idiom (epoch-proven r21).
// Schedule per iter: barx(top, NO drain) -> STAGE_V(j) -> vmcnt(4)+barx
// (K(j) landed; issued LAST iter after the post-QK barrier, when the K
// region is dead block-wide) -> QK+softmax+pack -> vmcnt(0)+barx (V
// visible, K region dead) -> STAGE_K(j+1) -> PV. Per-thread load FIFO at
// the K-wait: [K(j) x4 oldest, V(j) x4] -> vmcnt(4) retires K. Overwrite
// hazards: V guarded by top barrier (PV(j-1) complete), K guarded by the
// post-QK barrier. Inactive threads carry zero outstanding loads.
__global__ __launch_bounds__(512, 1) void attn_fwd_k(
    const short* __restrict__ Qb, const short* __restrict__ Kb,
    const short* __restrict__ Vtb, const float* __restrict__ gate_logits,
    short* __restrict__ attnb) {
    const int S = 2048;
    __shared__ short KV[2][16384];     // per-group: K 8192 | V 8192 shorts
    const int tid = threadIdx.x, lane = tid & 63;
    const int wid = tid >> 6;
    const int g = wid >> 2;
    const int hw = wid & 3;
    const int y = blockIdx.y;
    const int qt = (y < 32) ? (63 - y) : (y - 32);
    const int bhk = blockIdx.x;
    const int b = bhk >> 2, hk = bhk & 3;
    const int h = hk * 4 + hw;
    const int n = (qt + 2) >> 1;
    const int nh = (n + 1) >> 1, nl = n - nh;
    const int q0 = qt * 32;
    const int ql = lane & 31, hi = lane >> 5;
    const int qg = q0 + ql;
    const float THR = 11.5416f;        // 8 * log2(e)
    const float gl = gate_logits[h];
    const float gate = 1.f / (1.f + __expf(-gl));

    s16x8 qf[8];
#pragma unroll
    for (int kc = 0; kc < 8; ++kc)
        qf[kc] = *(const s16x8*)(Qb + (((size_t)(b * 16 + h) * S + qg) * 128 + hi * 8) + kc * 16);

    f32x16 ov[4];
#pragma unroll
    for (int dc = 0; dc < 4; ++dc)
#pragma unroll
        for (int r = 0; r < 16; ++r) ov[dc][r] = 0.f;
    float mrun = -3.0e38f, lrun = 0.f;

    const int g256 = tid & 255;
    const short* kg[4]; const short* vg[4]; int lb[4];
#pragma unroll
    for (int i = 0; i < 4; ++i) {
        int oo = (i * 256 + g256) * 8;
        lb[i] = (i * 256 + (g256 & ~63)) * 8;
        {
            int row = oo >> 7, col = oo & 127, ch = col >> 3;
            kg[i] = Kb + ((size_t)bhk * S + row) * 128 + ((ch ^ (row & 7)) << 3);
        }
        {
            int row = oo >> 6, col = oo & 63, ch = col >> 3;
            vg[i] = Vtb + ((size_t)bhk * 128 + row) * S + ((ch ^ (row & 7)) << 3);
        }
    }

#define STAGE_K(jj) do {                                                         \
        const int base_ = (jj) * 64;                                             \
        _Pragma("unroll")                                                        \
        for (int i_ = 0; i_ < 4; ++i_)                                           \
            gload_lds16(kg[i_] + (size_t)base_ * 128, &KV[g][lb[i_]]);           \
    } while (0)
#define STAGE_V(jj) do {                                                         \
        const int base_ = (jj) * 64;                                             \
        _Pragma("unroll")                                                        \
        for (int i_ = 0; i_ < 4; ++i_)                                           \
            gload_lds16(vg[i_] + base_, &KV[g][8192 + lb[i_]]);                  \
    } while (0)

    // prologue: first K tile for each group
    {
        const bool act0 = (g == 0) || (nl > 0);
        if (act0) STAGE_K((g == 0) ? 0 : nh);
    }

    for (int it = 0; it < nh; ++it) {
        const int j = (g == 0) ? it : (nh + it);
        const bool active = (g == 0) || (it < nl);
        if (it > 0) barx();                        // PV(j-1) done; V region dead (no drain!)
        if (active) STAGE_V(j);
        asm volatile("s_waitcnt vmcnt(4)" ::: "memory");   // K(j) retired
        barx();                                            // K writes visible
        const int j0 = j * 64;
        const bool have1 = (j0 + 32 <= q0 + 31);
        union { uint32_t u[4]; s16x8 v; } f00, f01, f10, f11;
        if (active) {
            const short* Ks = &KV[g][0];
            const bool fsub0 = (j0 + 31 <= q0);
            const bool fsub1 = (j0 + 63 <= q0);
            f32x16 s0, s1;
#pragma unroll
            for (int r = 0; r < 16; ++r) { s0[r] = 0.f; s1[r] = 0.f; }
            __builtin_amdgcn_s_setprio(1);
#pragma unroll
            for (int kc = 0; kc < 8; ++kc) {
                const int c = kc * 2 + hi;
                s16x8 kf0 = *(const s16x8*)&Ks[ql * 128 + ((c ^ (ql & 7)) << 3)];
                s0 = mfma32(kf0, qf[kc], s0);
            }
            if (have1) {
#pragma unroll
                for (int kc = 0; kc < 8; ++kc) {
                    const int c = kc * 2 + hi;
                    const int kr = 32 + ql;
                    s16x8 kf1 = *(const s16x8*)&Ks[kr * 128 + ((c ^ (kr & 7)) << 3)];
                    s1 = mfma32(kf1, qf[kc], s1);
                }
            }
            __builtin_amdgcn_s_setprio(0);
            float p0[16], p1[16];
            if (fsub0) {
#pragma unroll
                for (int r = 0; r < 16; ++r) p0[r] = s0[r];
            } else {
#pragma unroll
                for (int r = 0; r < 16; ++r) {
                    int kvg = j0 + ((r & 3) + 8 * (r >> 2) + 4 * hi);
                    p0[r] = (kvg <= qg) ? s0[r] : -3.0e38f;
                }
            }
            if (have1) {
                if (fsub1) {
#pragma unroll
                    for (int r = 0; r < 16; ++r) p1[r] = s1[r];
                } else {
#pragma unroll
                    for (int r = 0; r < 16; ++r) {
                        int kvg = j0 + 32 + ((r & 3) + 8 * (r >> 2) + 4 * hi);
                        p1[r] = (kvg <= qg) ? s1[r] : -3.0e38f;
                    }
                }
            }
            float a0 = fmaxf(p0[0], p0[1]),  a1 = fmaxf(p0[2], p0[3]);
            float a2 = fmaxf(p0[4], p0[5]),  a3 = fmaxf(p0[6], p0[7]);
            float a4 = fmaxf(p0[8], p0[9]),  a5 = fmaxf(p0[10], p0[11]);
            float a6 = fmaxf(p0[12], p0[13]), a7 = fmaxf(p0[14], p0[15]);
            float pmax = fmaxf(fmaxf(fmaxf(a0, a1), fmaxf(a2, a3)),
                               fmaxf(fmaxf(a4, a5), fmaxf(a6, a7)));
            if (have1) {
                float b0 = fmaxf(p1[0], p1[1]),  b1 = fmaxf(p1[2], p1[3]);
                float b2 = fmaxf(p1[4], p1[5]),  b3 = fmaxf(p1[6], p1[7]);
                float b4 = fmaxf(p1[8], p1[9]),  b5 = fmaxf(p1[10], p1[11]);
                float b6 = fmaxf(p1[12], p1[13]), b7 = fmaxf(p1[14], p1[15]);
                pmax = fmaxf(pmax, fmaxf(fmaxf(fmaxf(b0, b1), fmaxf(b2, b3)),
                                         fmaxf(fmaxf(b4, b5), fmaxf(b6, b7))));
            }
            pmax = cross_max(pmax);
            if (__any(pmax - mrun > THR)) {
                float mnew = fmaxf(mrun, pmax);
                float alpha = __builtin_exp2f(mrun - mnew);
                lrun *= alpha;
#pragma unroll
                for (int r = 0; r < 16; ++r) {
                    int cr = (r & 3) + 8 * (r >> 2) + 4 * hi;
                    float ar = __uint_as_float(
                        (uint32_t)__builtin_amdgcn_ds_bpermute(cr << 2, (int)__float_as_uint(alpha)));
                    ov[0][r] *= ar; ov[1][r] *= ar; ov[2][r] *= ar; ov[3][r] *= ar;
                }
                mrun = mnew;
            }
#pragma unroll
            for (int r = 0; r < 16; ++r) p0[r] = __builtin_exp2f(p0[r] - mrun);
            float ps;
            {
                float t0 = (p0[0] + p0[1]) + (p0[2] + p0[3]);
                float t1 = (p0[4] + p0[5]) + (p0[6] + p0[7]);
                float t2 = (p0[8] + p0[9]) + (p0[10] + p0[11]);
                float t3 = (p0[12] + p0[13]) + (p0[14] + p0[15]);
                ps = (t0 + t1) + (t2 + t3);
            }
            if (have1) {
#pragma unroll
                for (int r = 0; r < 16; ++r) p1[r] = __builtin_exp2f(p1[r] - mrun);
                float t0 = (p1[0] + p1[1]) + (p1[2] + p1[3]);
                float t1 = (p1[4] + p1[5]) + (p1[6] + p1[7]);
                float t2 = (p1[8] + p1[9]) + (p1[10] + p1[11]);
                float t3 = (p1[12] + p1[13]) + (p1[14] + p1[15]);
                ps += (t0 + t1) + (t2 + t3);
            }
            lrun += cross_sum(ps);
            {
                uint32_t w0 = cvtpk_bf16(p0[0], p0[1]),   w1 = cvtpk_bf16(p0[2], p0[3]);
                uint32_t w2 = cvtpk_bf16(p0[4], p0[5]),   w3 = cvtpk_bf16(p0[6], p0[7]);
                uint32_t w4 = cvtpk_bf16(p0[8], p0[9]),   w5 = cvtpk_bf16(p0[10], p0[11]);
                uint32_t w6 = cvtpk_bf16(p0[12], p0[13]), w7 = cvtpk_bf16(p0[14], p0[15]);
                u32x2 r02 = pl32swap(w0, w2); f00.u[0] = r02[0]; f00.u[2] = r02[1];
                u32x2 r13 = pl32swap(w1, w3); f00.u[1] = r13[0]; f00.u[3] = r13[1];
                u32x2 r46 = pl32swap(w4, w6); f01.u[0] = r46[0]; f01.u[2] = r46[1];
                u32x2 r57 = pl32swap(w5, w7); f01.u[1] = r57[0]; f01.u[3] = r57[1];
            }
            if (have1) {
                uint32_t w0 = cvtpk_bf16(p1[0], p1[1]),   w1 = cvtpk_bf16(p1[2], p1[3]);
                uint32_t w2 = cvtpk_bf16(p1[4], p1[5]),   w3 = cvtpk_bf16(p1[6], p1[7]);
                uint32_t w4 = cvtpk_bf16(p1[8], p1[9]),   w5 = cvtpk_bf16(p1[10], p1[11]);
                uint32_t w6 = cvtpk_bf16(p1[12], p1[13]), w7 = cvtpk_bf16(p1[14], p1[15]);
                u32x2 r02 = pl32swap(w0, w2); f10.u[0] = r02[0]; f10.u[2] = r02[1];
                u32x2 r13 = pl32swap(w1, w3); f10.u[1] = r13[0]; f10.u[3] = r13[1];
                u32x2 r46 = pl32swap(w4, w6); f11.u[0] = r46[0]; f11.u[2] = r46[1];
                u32x2 r57 = pl32swap(w5, w7); f11.u[1] = r57[0]; f11.u[3] = r57[1];
            }
        }
        asm volatile("s_waitcnt vmcnt(0)" ::: "memory");   // V loads retired
        barx();                                            // V visible; K region dead
        {
            const bool nok = (it + 1 < nh) && ((g == 0) || (it + 1 < nl));
            if (nok) STAGE_K(j + 1);                       // prefetch next K
        }
        if (active) {
            const short* Vs = &KV[g][8192];
            __builtin_amdgcn_s_setprio(1);
#pragma unroll
            for (int dc = 0; dc < 4; ++dc) {
                const int dd = dc * 32 + ql;
                const int sw = (dd & 7);
                s16x8 v0 = *(const s16x8*)&Vs[dd * 64 + (((hi) ^ sw) << 3)];
                ov[dc] = mfma32(f00.v, v0, ov[dc]);
                s16x8 v1 = *(const s16x8*)&Vs[dd * 64 + (((2 + hi) ^ sw) << 3)];
                ov[dc] = mfma32(f01.v, v1, ov[dc]);
                if (have1) {
                    s16x8 v2 = *(const s16x8*)&Vs[dd * 64 + (((4 + hi) ^ sw) << 3)];
                    ov[dc] = mfma32(f10.v, v2, ov[dc]);
                    s16x8 v3 = *(const s16x8*)&Vs[dd * 64 + (((6 + hi) ^ sw) << 3)];
                    ov[dc] = mfma32(f11.v, v3, ov[dc]);
                }
            }
            __builtin_amdgcn_s_setprio(0);
        }
    }

    // ---- merge: g1 partial -> g0, overlaid into dead KV ----
    __syncthreads();                               // all compute reads of KV done
    short* mbO = &KV[0][0];                        // 16384 shorts = 32KB (bf16 O)
    float* Msm2 = (float*)&KV[1][0];               // 256 floats
    float* Lsm2 = Msm2 + 256;                      // 256 floats
    if (g == 1) {
#pragma unroll
        for (int dc = 0; dc < 4; ++dc)
#pragma unroll
            for (int r = 0; r < 16; ++r)
                mbO[hw * 4096 + lane * 64 + dc * 16 + r] = (short)f2bf(ov[dc][r]);
        Msm2[hw * 64 + lane] = mrun;
        Lsm2[hw * 64 + lane] = lrun;
    }
    __syncthreads();
    if (g == 0) {
        const float m1 = Msm2[hw * 64 + lane];
        const float l1 = Lsm2[hw * 64 + lane];
        const float mm = fmaxf(mrun, m1);
        const float al0 = __builtin_exp2f(mrun - mm);
        const float al1 = __builtin_exp2f(m1 - mm);
        lrun = lrun * al0 + l1 * al1;
#pragma unroll
        for (int r = 0; r < 16; ++r) {
            int cr = (r & 3) + 8 * (r >> 2) + 4 * hi;
            float a0r = __uint_as_float(
                (uint32_t)__builtin_amdgcn_ds_bpermute(cr << 2, (int)__float_as_uint(al0)));
            float a1r = __uint_as_float(
                (uint32_t)__builtin_amdgcn_ds_bpermute(cr << 2, (int)__float_as_uint(al1)));
#pragma unroll
            for (int dc = 0; dc < 4; ++dc) {
                float o1 = bf2f((uint32_t)(unsigned short)mbO[hw * 4096 + lane * 64 + dc * 16 + r]);
                ov[dc][r] = ov[dc][r] * a0r + o1 * a1r;
            }
        }
        const float linv = gate / lrun;
#pragma unroll
        for (int r = 0; r < 16; ++r) {
            int cr = (r & 3) + 8 * (r >> 2) + 4 * hi;
            float sc = __uint_as_float(
                (uint32_t)__builtin_amdgcn_ds_bpermute(cr << 2, (int)__float_as_uint(linv)));
            int qrow = q0 + cr;
            short* orow = attnb + ((size_t)(b * S) + qrow) * 2048 + h * 128 + ql;
#pragma unroll
            for (int dc = 0; dc < 4; ++dc)
                orow[dc * 32] = (short)f2bf(ov[dc][r] * sc);
        }
    }
#undef STAGE_K
#undef STAGE_V
}

// ---------- launch ----------
extern "C" void kernel_launch(void* const* d_in, const int* in_sizes, int n_in,
                              void* d_out, int out_size, void* d_ws, size_t ws_size,
                              hipStream_t stream) {
    const float* x  = (const float*)d_in[0];
    const float* Wq = (const float*)d_in[1];
    const float* bq = (const float*)d_in[2];
    const float* Wk = (const float*)d_in[3];
    const float* bk = (const float*)d_in[4];
    const float* Wv = (const float*)d_in[5];
    const float* bv = (const float*)d_in[6];
    const float* Wo = (const float*)d_in[7];
    const float* bo = (const float*)d_in[8];
    const float* qn = (const float*)d_in[9];
    const float* kn = (const float*)d_in[10];
    const float* gl = (const float*)d_in[11];
    const int* sp   = (const int*)d_in[13];
    float* out = (float*)d_out;

    char* ws = (char*)d_ws;
    const size_t NEED = 96481280;
    if (ws_size < NEED) return;
    short* xb    = (short*)(ws + 0);            // 16 MiB, reused as Qb
    short* wqkvT = (short*)(ws + 16777216);     // 12 MiB
    short* woT   = (short*)(ws + 29360128);     // 8 MiB
    float* bqkv  = (float*)(ws + 37748736);     // 12 KiB
    short* Yb    = (short*)(ws + 37761024);     // 24 MiB bf16, head reused as attnb
    short* Kb    = (short*)(ws + 88092672);     // 4 MiB
    short* Vtb   = (short*)(ws + 92286976);     // 4 MiB
    short* Qb    = xb;
    short* attnb = Yb;

    f32_to_bf16_k<<<4096, 256, 0, stream>>>(x, xb, 1048576);
    transpose_f32_bf16_k<<<dim3(32, 32, 1), 256, 0, stream>>>(Wq, 0, 2048, wqkvT, 0, 2048);
    transpose_f32_bf16_k<<<dim3(8, 32, 1), 256, 0, stream>>>(Wk, 0, 512, wqkvT + (size_t)2048 * 2048, 0, 2048);
    transpose_f32_bf16_k<<<dim3(8, 32, 1), 256, 0, stream>>>(Wv, 0, 512, wqkvT + (size_t)2560 * 2048, 0, 2048);
    transpose_f32_bf16_k<<<dim3(32, 32, 1), 256, 0, stream>>>(Wo, 0, 2048, woT, 0, 2048);
    concat_bias_k<<<12, 256, 0, stream>>>(bq, bk, bv, bqkv);
    gemm256_k<0, true, 3><<<dim3(16, 16), 512, 0, stream>>>(xb, wqkvT, bqkv, Yb, 4096, 3072, 2048);
    qkv_post_k<<<4096, 256, 0, stream>>>(Yb, qn, kn, sp, Qb, Kb);
    transpose_bf16_k<<<dim3(8, 32, 2), 256, 0, stream>>>(
        Yb + 2560, (size_t)2048 * 3072, 3072, Vtb, (size_t)512 * 2048, 2048);
    attn_fwd_k<<<dim3(8, 64), 512, 0, stream>>>(Qb, Kb, Vtb, gl, attnb);
    gemm256_k<1, false, 2><<<dim3(16, 16), 512, 0, stream>>>(attnb, woT, bo, out, 4096, 2048, 2048);
}